// Round 3
// baseline (3457.836 us; speedup 1.0000x reference)
//
#include <hip/hip_runtime.h>
#include <hip/hip_bf16.h>
#include <cstdint>
#include <cstddef>

#define B_ 8
#define T_ 2048
#define C_ 2048
#define A_ 2048
#define H_ 32
#define BT_ (B_*T_)
#define SEG_ 64

typedef short short8 __attribute__((ext_vector_type(8)));
typedef float floatx4 __attribute__((ext_vector_type(4)));
typedef unsigned short ushortv8 __attribute__((ext_vector_type(8)));

__device__ __forceinline__ unsigned short f2bf(float f) {
  union { float f; uint32_t u; } a; a.f = f;
  uint32_t r = a.u + 0x7fffu + ((a.u >> 16) & 1u);   // RNE
  return (unsigned short)(r >> 16);
}
__device__ __forceinline__ float bf2f(unsigned short s) {
  union { uint32_t u; float f; } a; a.u = ((uint32_t)s) << 16;
  return a.f;
}

// invisible f32 store: keeps __restrict__ load pipelining intact (y rows are
// never re-read inside the scan kernel; a __syncthreads always separates a
// row's last read from its overwrite)
__device__ __forceinline__ void gst_f32(float val, float* addr) {
  asm volatile("global_store_dword %0, %1, off" :: "v"(addr), "v"(val));
}

// ---------------- weight prep: hi/lo bf16 split ----------------
__global__ void conv_hilo(const float* __restrict__ s, unsigned short* __restrict__ hi,
                          unsigned short* __restrict__ lo, int n) {
  int i = blockIdx.x * 256 + threadIdx.x;
  if (i < n) {
    float v = s[i];
    unsigned short h = f2bf(v);
    hi[i] = h;
    lo[i] = f2bf(v - bf2f(h));
  }
}

// src (2048 x NV) f32 -> dst (NP x 2048) bf16, rows >= NV zero-padded
__global__ void transpose_pad(const float* __restrict__ s, unsigned short* __restrict__ d, int NP, int NV) {
  int i = blockIdx.x * 256 + threadIdx.x;  // over NP*2048
  int n = i >> 11, kk = i & 2047;
  if (n < NP) d[i] = (n < NV) ? f2bf(s[kk * NV + n]) : (unsigned short)0;
}

// ---------------- token shift + maa_x mix ----------------
__global__ void shift_mix(const float* __restrict__ x, const float* __restrict__ tmx,
                          unsigned short* __restrict__ xxx) {
  size_t i4 = (size_t)blockIdx.x * 256 + threadIdx.x;   // over BT*C/4
  size_t i = i4 * 4;
  int c = (int)(i & 2047);
  int t = (int)((i >> 11) & 2047);
  float4 xv = *(const float4*)&x[i];
  float4 pv = make_float4(0.f, 0.f, 0.f, 0.f);
  if (t > 0) pv = *(const float4*)&x[i - 2048];
  float4 tv = *(const float4*)&tmx[c];
  ushort4 m;
  m.x = f2bf(xv.x + (pv.x - xv.x) * tv.x);
  m.y = f2bf(xv.y + (pv.y - xv.y) * tv.y);
  m.z = f2bf(xv.z + (pv.z - xv.z) * tv.z);
  m.w = f2bf(xv.w + (pv.w - xv.w) * tv.w);
  *(ushort4*)&xxx[i] = m;
}

// ---------------- async global->LDS helper ----------------
__device__ __forceinline__ void gll16(const void* g, void* l) {
  __builtin_amdgcn_global_load_lds(
      (const __attribute__((address_space(1))) void*)g,
      (__attribute__((address_space(3))) void*)l, 16, 0, 0);
}

// ---------------- plain bf16 GEMM (small-N lora paths): C = A * B^T ----------------
// EPI: 2 = tanh->f32
template<int EPI>
__global__ __launch_bounds__(256)
void gemm_bt(const unsigned short* __restrict__ Am, const unsigned short* __restrict__ Bm,
             void* __restrict__ Cp, int M, int N, int K) {
  __shared__ unsigned short As[128 * 32];
  __shared__ unsigned short Bs[128 * 32];
  const int tid = threadIdx.x;
  const int wid = tid >> 6, lane = tid & 63;
  const int quad = lane >> 4, l15 = lane & 15;
  const long bm = (long)blockIdx.x * 128, bn = (long)blockIdx.y * 128;
  const int wm = (wid & 1) * 64, wn = (wid >> 1) * 64;

  floatx4 acc[4][4];
#pragma unroll
  for (int a = 0; a < 4; a++)
#pragma unroll
    for (int b = 0; b < 4; b++) { floatx4 z = {0.f, 0.f, 0.f, 0.f}; acc[a][b] = z; }

  const int stg_row = wid * 32 + (lane >> 2);
  const int stg_k   = (lane & 3) * 8;
  const int stg_lds = wid * 1024 + lane * 8;

  for (int k0 = 0; k0 < K; k0 += 32) {
    __syncthreads();
#pragma unroll
    for (int p = 0; p < 2; ++p) {
      gll16(Am + (bm + stg_row + p * 16) * (long)K + k0 + stg_k, &As[stg_lds + p * 512]);
      gll16(Bm + (bn + stg_row + p * 16) * (long)K + k0 + stg_k, &Bs[stg_lds + p * 512]);
    }
    __syncthreads();

    short8 af[4], bfr[4];
#pragma unroll
    for (int mi = 0; mi < 4; mi++) af[mi] = *(const short8*)&As[(wm + mi * 16 + l15) * 32 + quad * 8];
#pragma unroll
    for (int ni = 0; ni < 4; ni++) bfr[ni] = *(const short8*)&Bs[(wn + ni * 16 + l15) * 32 + quad * 8];
#pragma unroll
    for (int mi = 0; mi < 4; mi++)
#pragma unroll
      for (int ni = 0; ni < 4; ni++)
        acc[mi][ni] = __builtin_amdgcn_mfma_f32_16x16x32_bf16(af[mi], bfr[ni], acc[mi][ni], 0, 0, 0);
  }

#pragma unroll
  for (int mi = 0; mi < 4; mi++)
#pragma unroll
    for (int ni = 0; ni < 4; ni++)
#pragma unroll
      for (int vv = 0; vv < 4; ++vv) {
        long row = bm + wm + mi * 16 + quad * 4 + vv;
        long col = bn + wn + ni * 16 + l15;
        float val = acc[mi][ni][vv];
        if (EPI == 2) ((float*)Cp)[row * N + col] = tanhf(val);
      }
}

// ---------------- split-B GEMM: C = A * (Bh+Bl)^T  (weight-exact) ----------------
// EPI: 0 = ->bf16, 1 = silu->bf16, 3 = ->f32
template<int EPI>
__global__ __launch_bounds__(256)
void gemm_sb(const unsigned short* __restrict__ Am, const unsigned short* __restrict__ Bhm,
             const unsigned short* __restrict__ Blm, void* __restrict__ Cp, int M, int N, int K) {
  __shared__ unsigned short As[128 * 32];
  __shared__ unsigned short Bhs[128 * 32];
  __shared__ unsigned short Bls[128 * 32];
  const int tid = threadIdx.x;
  const int wid = tid >> 6, lane = tid & 63;
  const int quad = lane >> 4, l15 = lane & 15;
  const long bm = (long)blockIdx.x * 128, bn = (long)blockIdx.y * 128;
  const int wm = (wid & 1) * 64, wn = (wid >> 1) * 64;

  floatx4 acc[4][4];
#pragma unroll
  for (int a = 0; a < 4; a++)
#pragma unroll
    for (int b = 0; b < 4; b++) { floatx4 z = {0.f, 0.f, 0.f, 0.f}; acc[a][b] = z; }

  const int stg_row = wid * 32 + (lane >> 2);
  const int stg_k   = (lane & 3) * 8;
  const int stg_lds = wid * 1024 + lane * 8;

  for (int k0 = 0; k0 < K; k0 += 32) {
    __syncthreads();
#pragma unroll
    for (int p = 0; p < 2; ++p) {
      const long rowA = (bm + stg_row + p * 16) * (long)K + k0 + stg_k;
      const long rowB = (bn + stg_row + p * 16) * (long)K + k0 + stg_k;
      gll16(Am  + rowA, &As [stg_lds + p * 512]);
      gll16(Bhm + rowB, &Bhs[stg_lds + p * 512]);
      gll16(Blm + rowB, &Bls[stg_lds + p * 512]);
    }
    __syncthreads();

    short8 af[4], bh[4], bl[4];
#pragma unroll
    for (int mi = 0; mi < 4; mi++) af[mi] = *(const short8*)&As[(wm + mi * 16 + l15) * 32 + quad * 8];
#pragma unroll
    for (int ni = 0; ni < 4; ni++) {
      bh[ni] = *(const short8*)&Bhs[(wn + ni * 16 + l15) * 32 + quad * 8];
      bl[ni] = *(const short8*)&Bls[(wn + ni * 16 + l15) * 32 + quad * 8];
    }
#pragma unroll
    for (int mi = 0; mi < 4; mi++)
#pragma unroll
      for (int ni = 0; ni < 4; ni++) {
        acc[mi][ni] = __builtin_amdgcn_mfma_f32_16x16x32_bf16(af[mi], bh[ni], acc[mi][ni], 0, 0, 0);
        acc[mi][ni] = __builtin_amdgcn_mfma_f32_16x16x32_bf16(af[mi], bl[ni], acc[mi][ni], 0, 0, 0);
      }
  }

#pragma unroll
  for (int mi = 0; mi < 4; mi++)
#pragma unroll
    for (int ni = 0; ni < 4; ni++)
#pragma unroll
      for (int vv = 0; vv < 4; ++vv) {
        long row = bm + wm + mi * 16 + quad * 4 + vv;
        long col = bn + wn + ni * 16 + l15;
        float val = acc[mi][ni][vv];
        if (EPI == 0) {
          ((unsigned short*)Cp)[row * N + col] = f2bf(val);
        } else if (EPI == 1) {
          float s = val / (1.f + __expf(-val));
          ((unsigned short*)Cp)[row * N + col] = f2bf(s);
        } else {
          ((float*)Cp)[row * N + col] = val;
        }
      }
}

// ---------------- 3-term GEMM: C = Ah*Bh^T + Ah*Bl^T + Al*Bh^T -> f32 (final proj) ----------------
__global__ __launch_bounds__(256)
void gemm_s3(const unsigned short* __restrict__ Ahm, const unsigned short* __restrict__ Alm,
             const unsigned short* __restrict__ Bhm, const unsigned short* __restrict__ Blm,
             float* __restrict__ Cp, int M, int N, int K) {
  __shared__ unsigned short Ahs[128 * 32];
  __shared__ unsigned short Als[128 * 32];
  __shared__ unsigned short Bhs[128 * 32];
  __shared__ unsigned short Bls[128 * 32];
  const int tid = threadIdx.x;
  const int wid = tid >> 6, lane = tid & 63;
  const int quad = lane >> 4, l15 = lane & 15;
  const long bm = (long)blockIdx.x * 128, bn = (long)blockIdx.y * 128;
  const int wm = (wid & 1) * 64, wn = (wid >> 1) * 64;

  floatx4 acc[4][4];
#pragma unroll
  for (int a = 0; a < 4; a++)
#pragma unroll
    for (int b = 0; b < 4; b++) { floatx4 z = {0.f, 0.f, 0.f, 0.f}; acc[a][b] = z; }

  const int stg_row = wid * 32 + (lane >> 2);
  const int stg_k   = (lane & 3) * 8;
  const int stg_lds = wid * 1024 + lane * 8;

  for (int k0 = 0; k0 < K; k0 += 32) {
    __syncthreads();
#pragma unroll
    for (int p = 0; p < 2; ++p) {
      const long rowA = (bm + stg_row + p * 16) * (long)K + k0 + stg_k;
      const long rowB = (bn + stg_row + p * 16) * (long)K + k0 + stg_k;
      gll16(Ahm + rowA, &Ahs[stg_lds + p * 512]);
      gll16(Alm + rowA, &Als[stg_lds + p * 512]);
      gll16(Bhm + rowB, &Bhs[stg_lds + p * 512]);
      gll16(Blm + rowB, &Bls[stg_lds + p * 512]);
    }
    __syncthreads();

    short8 ah[4], al[4], bh[4], bl[4];
#pragma unroll
    for (int mi = 0; mi < 4; mi++) {
      ah[mi] = *(const short8*)&Ahs[(wm + mi * 16 + l15) * 32 + quad * 8];
      al[mi] = *(const short8*)&Als[(wm + mi * 16 + l15) * 32 + quad * 8];
    }
#pragma unroll
    for (int ni = 0; ni < 4; ni++) {
      bh[ni] = *(const short8*)&Bhs[(wn + ni * 16 + l15) * 32 + quad * 8];
      bl[ni] = *(const short8*)&Bls[(wn + ni * 16 + l15) * 32 + quad * 8];
    }
#pragma unroll
    for (int mi = 0; mi < 4; mi++)
#pragma unroll
      for (int ni = 0; ni < 4; ni++) {
        acc[mi][ni] = __builtin_amdgcn_mfma_f32_16x16x32_bf16(ah[mi], bh[ni], acc[mi][ni], 0, 0, 0);
        acc[mi][ni] = __builtin_amdgcn_mfma_f32_16x16x32_bf16(ah[mi], bl[ni], acc[mi][ni], 0, 0, 0);
        acc[mi][ni] = __builtin_amdgcn_mfma_f32_16x16x32_bf16(al[mi], bh[ni], acc[mi][ni], 0, 0, 0);
      }
  }

#pragma unroll
  for (int mi = 0; mi < 4; mi++)
#pragma unroll
    for (int ni = 0; ni < 4; ni++)
#pragma unroll
      for (int vv = 0; vv < 4; ++vv) {
        long row = bm + wm + mi * 16 + quad * 4 + vv;
        long col = bn + wn + ni * 16 + l15;
        Cp[row * N + col] = acc[mi][ni][vv];
      }
}

// ---------------- fused LoRA-mix (xx recomputed inline) ----------------
__global__ __launch_bounds__(256)
void mix_lora(const float* __restrict__ x,
              const float* __restrict__ m5, const float* __restrict__ w2,
              const float* __restrict__ tmw, const float* __restrict__ tmk,
              const float* __restrict__ tmv, const float* __restrict__ tmr,
              const float* __restrict__ tmg,
              unsigned short* __restrict__ xw, unsigned short* __restrict__ xk,
              unsigned short* __restrict__ xv, unsigned short* __restrict__ xr,
              unsigned short* __restrict__ xg) {
  const int bt0 = blockIdx.x * 16;
  const int tid = threadIdx.x;
  const float* tms[5] = {tmw, tmk, tmv, tmr, tmg};
  unsigned short* outs[5] = {xw, xk, xv, xr, xg};
  for (int cc = 0; cc < 8; ++cc) {
    const int c = cc * 256 + tid;
    float xv_[16], xxv_[16];
#pragma unroll
    for (int b = 0; b < 16; b++) {
      const int bt = bt0 + b;
      size_t idx = ((size_t)bt << 11) + c;
      float xc = x[idx];
      float xp = ((bt & 2047) > 0) ? x[idx - 2048] : 0.f;
      xv_[b] = xc; xxv_[b] = xp - xc;
    }
#pragma unroll
    for (int f = 0; f < 5; ++f) {
      const float tmf = tms[f][c];
      float acc[16];
#pragma unroll
      for (int b = 0; b < 16; b++) acc[b] = 0.f;
      for (int dc = 0; dc < 8; ++dc) {
        float wv0 = w2[((size_t)(f * 32 + dc * 4 + 0) << 11) + c];
        float wv1 = w2[((size_t)(f * 32 + dc * 4 + 1) << 11) + c];
        float wv2 = w2[((size_t)(f * 32 + dc * 4 + 2) << 11) + c];
        float wv3 = w2[((size_t)(f * 32 + dc * 4 + 3) << 11) + c];
#pragma unroll
        for (int b = 0; b < 16; b++) {
          float4 mv = *(const float4*)&m5[((size_t)(bt0 + b) << 8) + f * 32 + dc * 4];
          acc[b] += mv.x * wv0 + mv.y * wv1 + mv.z * wv2 + mv.w * wv3;
        }
      }
#pragma unroll
      for (int b = 0; b < 16; b++) {
        size_t idx = ((size_t)(bt0 + b) << 11) + c;
        outs[f][idx] = f2bf(xv_[b] + xxv_[b] * (tmf + acc[b]));
      }
    }
  }
}

// ---------------- decay: dec = exp(-exp(td + t1 @ decay_w2)) (f32) ----------------
__global__ __launch_bounds__(256)
void decay_kernel(const float* __restrict__ t1, const float* __restrict__ w2d,
                  const float* __restrict__ td, float* __restrict__ dec) {
  const int bt0 = blockIdx.x * 16;
  const int tid = threadIdx.x;
  for (int cc = 0; cc < 8; ++cc) {
    const int a = cc * 256 + tid;
    const float tda = td[a];
    float acc[16];
#pragma unroll
    for (int b = 0; b < 16; b++) acc[b] = 0.f;
    for (int dc = 0; dc < 16; ++dc) {
      float wv0 = w2d[((size_t)(dc * 4 + 0) << 11) + a];
      float wv1 = w2d[((size_t)(dc * 4 + 1) << 11) + a];
      float wv2 = w2d[((size_t)(dc * 4 + 2) << 11) + a];
      float wv3 = w2d[((size_t)(dc * 4 + 3) << 11) + a];
#pragma unroll
      for (int b = 0; b < 16; b++) {
        float4 mv = *(const float4*)&t1[((size_t)(bt0 + b) << 7) + dc * 4];
        acc[b] += mv.x * wv0 + mv.y * wv1 + mv.z * wv2 + mv.w * wv3;
      }
    }
#pragma unroll
    for (int b = 0; b < 16; b++) {
      dec[((size_t)(bt0 + b) << 11) + a] = __expf(-__expf(tda + acc[b]));
    }
  }
}

// ---------------- WKV6 scan, barrier-free j-split, 16 waves ----------------
// block = one (b,h), 1024 threads = 16 waves (4 waves/SIMD for latency hiding).
// Wave w owns value-columns [4w,4w+4); lane: g = lane>>2 (i-group of 4
// key-channels), jl = lane&3 (column). S[4] per lane; block total = 64x64
// state, no duplication. i-reduction = 4 intra-wave shfl_xor (masks 4/8/16/32).
// No per-step barriers: y[t] written (invisible asm store) to dec row t-SEG
// (dead after read) / scratch ybuf0 for t<SEG. One __syncthreads per SEG
// steps bounds wave skew AND drains each wave's prefetch loads (vmcnt(0))
// so reads of a dec row always precede its overwrite.
// 4-deep register prefetch (rows t..t+3 in flight per wave).
template<int KF32>
__global__ __launch_bounds__(1024, 1)
void wkv6_scan(const unsigned short* __restrict__ r, const unsigned short* __restrict__ k16,
               const float* __restrict__ k32, const float* __restrict__ v,
               const float* __restrict__ dec, const float* __restrict__ u,
               float* __restrict__ ybuf0, float* ydec) {
  const int bh = blockIdx.x;
  const int b = bh >> 5, h = bh & 31;
  const int tid = threadIdx.x;
  const int w = tid >> 6, lane = tid & 63;
  const int g = lane >> 2, jl = lane & 3;
  const int ci = g * 4;            // i-offset of this lane's key-channel group
  const int j = w * 4 + jl;        // value-column within head
  const int cj = h * 64 + j;

  float S[4];
#pragma unroll
  for (int m = 0; m < 4; ++m) S[m] = 0.f;
  float uu[4];
#pragma unroll
  for (int m = 0; m < 4; ++m) uu[m] = u[h * 64 + ci + m];

  const size_t base = ((size_t)b * T_) * (size_t)A_ + h * 64;
  float* yb0 = ybuf0 + ((size_t)b * SEG_) * (size_t)A_ + cj;
  float* ydb = ydec + ((ptrdiff_t)b * T_ - SEG_) * (ptrdiff_t)A_ + cj;

#define DECL_BUF(N) ushort4 rv##N; ushort4 kh##N; float4 ka##N, da##N; float vv##N;
#define LOAD_BUF(N, TI) do {                                                    \
    const size_t o_ = base + (size_t)(TI) * A_;                                 \
    rv##N = *(const ushort4*)&r[o_ + ci];                                       \
    if (KF32) ka##N = *(const float4*)&k32[o_ + ci];                            \
    else      kh##N = *(const ushort4*)&k16[o_ + ci];                           \
    da##N = *(const float4*)&dec[o_ + ci];                                      \
    vv##N = v[o_ + j];                                                          \
  } while (0)
#define COMP_BUF(N, TI) do {                                                    \
    float rr_[4], kk_[4], dd_[4];                                               \
    rr_[0] = bf2f(rv##N.x); rr_[1] = bf2f(rv##N.y);                             \
    rr_[2] = bf2f(rv##N.z); rr_[3] = bf2f(rv##N.w);                             \
    dd_[0] = da##N.x; dd_[1] = da##N.y; dd_[2] = da##N.z; dd_[3] = da##N.w;     \
    if (KF32) { kk_[0] = ka##N.x; kk_[1] = ka##N.y;                             \
                kk_[2] = ka##N.z; kk_[3] = ka##N.w; }                           \
    else      { kk_[0] = bf2f(kh##N.x); kk_[1] = bf2f(kh##N.y);                 \
                kk_[2] = bf2f(kh##N.z); kk_[3] = bf2f(kh##N.w); }               \
    float y_ = 0.f;                                                             \
    _Pragma("unroll")                                                           \
    for (int m = 0; m < 4; ++m) {                                               \
      float kv = kk_[m] * vv##N;                                                \
      y_ = fmaf(rr_[m], fmaf(uu[m], kv, S[m]), y_);                             \
      S[m] = fmaf(dd_[m], S[m], kv);                                            \
    }                                                                           \
    y_ += __shfl_xor(y_, 4, 64);                                                \
    y_ += __shfl_xor(y_, 8, 64);                                                \
    y_ += __shfl_xor(y_, 16, 64);                                               \
    y_ += __shfl_xor(y_, 32, 64);                                               \
    if (lane < 4) {                                                             \
      float* yo_ = (((TI) < SEG_) ? yb0 : ydb) + (size_t)(TI) * A_;             \
      gst_f32(y_, yo_);                                                         \
    }                                                                           \
  } while (0)

  DECL_BUF(0) DECL_BUF(1) DECL_BUF(2) DECL_BUF(3)
  LOAD_BUF(0, 0); LOAD_BUF(1, 1); LOAD_BUF(2, 2); LOAD_BUF(3, 3);

  for (int s = 0; s < T_ / SEG_; ++s) {
    if (s) __syncthreads();   // bounds wave skew: reads of a row precede its y-overwrite
    const int t0 = s * SEG_;
    for (int tt = 0; tt < SEG_; tt += 4) {
      const int t = t0 + tt;
      const int n0 = (t + 4 < T_) ? t + 4 : T_ - 1;
      const int n1 = (t + 5 < T_) ? t + 5 : T_ - 1;
      const int n2 = (t + 6 < T_) ? t + 6 : T_ - 1;
      const int n3 = (t + 7 < T_) ? t + 7 : T_ - 1;
      COMP_BUF(0, t);     LOAD_BUF(0, n0);
      COMP_BUF(1, t + 1); LOAD_BUF(1, n1);
      COMP_BUF(2, t + 2); LOAD_BUF(2, n2);
      COMP_BUF(3, t + 3); LOAD_BUF(3, n3);
    }
  }
  asm volatile("s_waitcnt vmcnt(0)" ::: "memory");   // drain invisible stores
#undef DECL_BUF
#undef LOAD_BUF
#undef COMP_BUF
}

// ---------------- GroupNorm*g epilogue: z = GN(y)*g -> z_hi (over g), z_lo (over r) ----------------
__global__ __launch_bounds__(256)
void gn_fuse(const float* __restrict__ ydec, const float* __restrict__ ybuf0,
             unsigned short* __restrict__ gz, unsigned short* __restrict__ zlo,
             const float* __restrict__ lnw, const float* __restrict__ lnb) {
  const int bt = blockIdx.x;
  const int t = bt & (T_ - 1), b = bt >> 11;
  const int w = threadIdx.x >> 6, j = threadIdx.x & 63;
  const float* ys = (t < SEG_) ? (ybuf0 + ((size_t)b * SEG_ + t) * (size_t)A_)
                               : (ydec + ((size_t)bt - SEG_) * (size_t)A_);
  const size_t rowo = (size_t)bt * (size_t)A_;
#pragma unroll
  for (int hh = 0; hh < 8; ++hh) {
    const int h = hh * 4 + w;
    const int c = h * 64 + j;
    float yj = ys[c];
    float sm = yj, sq = yj * yj;
#pragma unroll
    for (int d = 32; d > 0; d >>= 1) {
      sm += __shfl_xor(sm, d, 64);
      sq += __shfl_xor(sq, d, 64);
    }
    float mu = sm * (1.f / 64.f);
    float var = sq * (1.f / 64.f) - mu * mu;
    float rs = rsqrtf(var + 6.4e-4f);   // EPS = 1e-5 * 64
    float yn = (yj - mu) * rs * lnw[c] + lnb[c];
    float z = yn * bf2f(gz[rowo + c]);
    unsigned short zh = f2bf(z);
    gz[rowo + c] = zh;
    zlo[rowo + c] = f2bf(z - bf2f(zh));
  }
}

// ---------------- launch ----------------
extern "C" void kernel_launch(void* const* d_in, const int* in_sizes, int n_in,
                              void* d_out, int out_size, void* d_ws, size_t ws_size,
                              hipStream_t stream) {
  (void)in_sizes; (void)n_in; (void)out_size;
  const float* x   = (const float*)d_in[0];
  const float* tmx = (const float*)d_in[1];
  const float* tmw = (const float*)d_in[2];
  const float* tmk = (const float*)d_in[3];
  const float* tmv = (const float*)d_in[4];
  const float* tmr = (const float*)d_in[5];
  const float* tmg = (const float*)d_in[6];
  const float* w1  = (const float*)d_in[7];   // (C,160)
  const float* w2  = (const float*)d_in[8];   // (5,32,C)
  const float* td  = (const float*)d_in[9];   // (A)
  const float* dw1 = (const float*)d_in[10];  // (C,64)
  const float* dw2 = (const float*)d_in[11];  // (64,A)
  const float* u   = (const float*)d_in[12];  // (H,N)
  const float* Wr  = (const float*)d_in[13];
  const float* Wk  = (const float*)d_in[14];
  const float* Wv  = (const float*)d_in[15];
  const float* Wg  = (const float*)d_in[16];
  const float* Wo  = (const float*)d_in[17];
  const float* lnw = (const float*)d_in[18];
  const float* lnb = (const float*)d_in[19];

  char* ws = (char*)d_ws;
  const size_t MB = 1024 * 1024;
  // 472MB layout (proven safe footprint), lifetime-overlapped:
  // [0,64)    U0: xxx -> g -> z_hi (in place)
  // [64,80)       m5 (f32, 16MB) -> later v-f32 lower half spans [64,128)
  // [128,192) U2: bxk (w1T scratch at [128,129) pre-mix) -> v-f32 upper half
  // [192,256) U3: bxv -> dec lower half
  // [256,320) U4: bxw -> dec upper half     (dec = [192,320) f32; y overlays dec rows t-SEG)
  // [320,384) U5: bxg -> r -> z_lo overlay (gn kernel)
  // [384,448) U6: bxr -> k (bf16, L0)
  // [448,464)     W_hi/W_lo scratch (dw1T pre) -> ybuf0 (4MB, scan) -> W_hi/W_lo (Wo)
  // [464,472)     t1 (f32, 8MB)
  unsigned short* xxx  = (unsigned short*)(ws + 0 * MB);
  unsigned short* gb   = (unsigned short*)(ws + 0 * MB);     // z_hi
  float*          m5   = (float*)(ws + 64 * MB);
  float*          vf   = (float*)(ws + 64 * MB);             // v f32 [64,192)
  unsigned short* w1T  = (unsigned short*)(ws + 128 * MB);
  unsigned short* bxk  = (unsigned short*)(ws + 128 * MB);
  unsigned short* bxv  = (unsigned short*)(ws + 192 * MB);
  float*          decb = (float*)(ws + 192 * MB);            // dec f32 [192,320)
  unsigned short* bxw  = (unsigned short*)(ws + 256 * MB);
  unsigned short* bxg  = (unsigned short*)(ws + 320 * MB);
  unsigned short* rb   = (unsigned short*)(ws + 320 * MB);   // r, then z_lo overlay
  unsigned short* bxr  = (unsigned short*)(ws + 384 * MB);
  unsigned short* kb   = (unsigned short*)(ws + 384 * MB);   // k bf16 (L0)
  unsigned short* dw1T = (unsigned short*)(ws + 448 * MB);
  unsigned short* Whi  = (unsigned short*)(ws + 448 * MB);
  unsigned short* Wlo  = (unsigned short*)(ws + 456 * MB);
  float*          ybuf0= (float*)(ws + 448 * MB);            // 4MB, scan-time only
  float*          t1   = (float*)(ws + 464 * MB);
  // optional upgrade: k in f32 at [480,608) if workspace allows (runtime-constant branch)
  const bool kf32 = ws_size >= (size_t)616 * MB;
  float* kf = (float*)(ws + 480 * MB);

  const int nW = A_ * C_;  // 4.19M elements
  const size_t EBT = (size_t)BT_ * C_;

  // 1. token-shift mix -> xxx
  shift_mix<<<(int)(EBT / 4 / 256), 256, 0, stream>>>(x, tmx, xxx);

  // 2. m5 = tanh(xxx @ maa_w1) padded N=256
  transpose_pad<<<(256 * 2048) / 256, 256, 0, stream>>>(w1, w1T, 256, 160);
  gemm_bt<2><<<dim3(BT_ / 128, 2), 256, 0, stream>>>(xxx, w1T, m5, BT_, 256, 2048);

  // 3. five mixed inputs
  mix_lora<<<BT_ / 16, 256, 0, stream>>>(x, m5, w2, tmw, tmk, tmv, tmr, tmg,
                                         bxw, bxk, bxv, bxr, bxg);

  // 4. t1 = tanh(xw @ decay_w1) padded N=128
  transpose_pad<<<(128 * 2048) / 256, 256, 0, stream>>>(dw1, dw1T, 128, 64);
  gemm_bt<2><<<dim3(BT_ / 128, 1), 256, 0, stream>>>(bxw, dw1T, t1, BT_, 128, 2048);

  // 5-8. projections with split-exact weights (order matters for slot recycling)
  conv_hilo<<<nW / 256, 256, 0, stream>>>(Wg, Whi, Wlo, nW);
  gemm_sb<1><<<dim3(BT_ / 128, 16), 256, 0, stream>>>(bxg, Whi, Wlo, gb, BT_, 2048, 2048);
  conv_hilo<<<nW / 256, 256, 0, stream>>>(Wr, Whi, Wlo, nW);
  gemm_sb<0><<<dim3(BT_ / 128, 16), 256, 0, stream>>>(bxr, Whi, Wlo, rb, BT_, 2048, 2048);
  conv_hilo<<<nW / 256, 256, 0, stream>>>(Wk, Whi, Wlo, nW);
  if (kf32) {
    gemm_sb<3><<<dim3(BT_ / 128, 16), 256, 0, stream>>>(bxk, Whi, Wlo, kf, BT_, 2048, 2048);
  } else {
    gemm_sb<0><<<dim3(BT_ / 128, 16), 256, 0, stream>>>(bxk, Whi, Wlo, kb, BT_, 2048, 2048);
  }
  conv_hilo<<<nW / 256, 256, 0, stream>>>(Wv, Whi, Wlo, nW);
  gemm_sb<3><<<dim3(BT_ / 128, 16), 256, 0, stream>>>(bxv, Whi, Wlo, vf, BT_, 2048, 2048);

  // 9. dec (after bxv/bxw are dead; overlays them)
  decay_kernel<<<BT_ / 16, 256, 0, stream>>>(t1, dw2, td, decb);

  // 10. WKV6 scan (barrier-free, 16 waves): y -> dec-row overlay + ybuf0 for t<SEG
  if (kf32) {
    wkv6_scan<1><<<256, 1024, 0, stream>>>(rb, kb, kf, vf, decb, u, ybuf0, decb);
  } else {
    wkv6_scan<0><<<256, 1024, 0, stream>>>(rb, kb, kf, vf, decb, u, ybuf0, decb);
  }

  // 10b. GroupNorm*g epilogue -> z_hi (over g), z_lo (over r)
  gn_fuse<<<BT_, 256, 0, stream>>>(decb, ybuf0, gb, rb, lnw, lnb);

  // 11. output projection: (z_hi + z_lo) @ (Wo_hi + Wo_lo)^T -> d_out (f32)
  conv_hilo<<<nW / 256, 256, 0, stream>>>(Wo, Whi, Wlo, nW);
  gemm_s3<<<dim3(BT_ / 128, 16), 256, 0, stream>>>(gb, rb, Whi, Wlo, (float*)d_out, BT_, 2048, 2048);
}

// Round 4
// 3015.705 us; speedup vs baseline: 1.1466x; 1.1466x over previous
//
#include <hip/hip_runtime.h>
#include <hip/hip_bf16.h>
#include <cstdint>
#include <cstddef>

#define B_ 8
#define T_ 2048
#define C_ 2048
#define A_ 2048
#define H_ 32
#define BT_ (B_*T_)

typedef short short8 __attribute__((ext_vector_type(8)));
typedef float floatx4 __attribute__((ext_vector_type(4)));

__device__ __forceinline__ unsigned short f2bf(float f) {
  union { float f; uint32_t u; } a; a.f = f;
  uint32_t r = a.u + 0x7fffu + ((a.u >> 16) & 1u);   // RNE
  return (unsigned short)(r >> 16);
}
__device__ __forceinline__ float bf2f(unsigned short s) {
  union { uint32_t u; float f; } a; a.u = ((uint32_t)s) << 16;
  return a.f;
}
__device__ __forceinline__ void split_hl(float v, unsigned short& hh, unsigned short& ll) {
  hh = f2bf(v);
  ll = f2bf(v - bf2f(hh));
}
// XOR-swizzled index into a row-major [64][64] bf16 LDS tile (G4 recipe)
__device__ __forceinline__ int swz(int row, int col) {
  return row * 64 + (col ^ ((row & 7) << 3));
}
__device__ __forceinline__ short8 ldfrag(const unsigned short* M, int row, int col8) {
  return *(const short8*)&M[row * 64 + (col8 ^ ((row & 7) << 3))];
}

// ---------------- weight prep: hi/lo bf16 split ----------------
__global__ void conv_hilo(const float* __restrict__ s, unsigned short* __restrict__ hi,
                          unsigned short* __restrict__ lo, int n) {
  int i = blockIdx.x * 256 + threadIdx.x;
  if (i < n) {
    float v = s[i];
    unsigned short h = f2bf(v);
    hi[i] = h;
    lo[i] = f2bf(v - bf2f(h));
  }
}

// src (2048 x NV) f32 -> dst (NP x 2048) bf16, rows >= NV zero-padded
__global__ void transpose_pad(const float* __restrict__ s, unsigned short* __restrict__ d, int NP, int NV) {
  int i = blockIdx.x * 256 + threadIdx.x;  // over NP*2048
  int n = i >> 11, kk = i & 2047;
  if (n < NP) d[i] = (n < NV) ? f2bf(s[kk * NV + n]) : (unsigned short)0;
}

// ---------------- token shift + maa_x mix ----------------
__global__ void shift_mix(const float* __restrict__ x, const float* __restrict__ tmx,
                          unsigned short* __restrict__ xxx) {
  size_t i4 = (size_t)blockIdx.x * 256 + threadIdx.x;   // over BT*C/4
  size_t i = i4 * 4;
  int c = (int)(i & 2047);
  int t = (int)((i >> 11) & 2047);
  float4 xv = *(const float4*)&x[i];
  float4 pv = make_float4(0.f, 0.f, 0.f, 0.f);
  if (t > 0) pv = *(const float4*)&x[i - 2048];
  float4 tv = *(const float4*)&tmx[c];
  ushort4 m;
  m.x = f2bf(xv.x + (pv.x - xv.x) * tv.x);
  m.y = f2bf(xv.y + (pv.y - xv.y) * tv.y);
  m.z = f2bf(xv.z + (pv.z - xv.z) * tv.z);
  m.w = f2bf(xv.w + (pv.w - xv.w) * tv.w);
  *(ushort4*)&xxx[i] = m;
}

// ---------------- async global->LDS helper ----------------
__device__ __forceinline__ void gll16(const void* g, void* l) {
  __builtin_amdgcn_global_load_lds(
      (const __attribute__((address_space(1))) void*)g,
      (__attribute__((address_space(3))) void*)l, 16, 0, 0);
}

// ---------------- plain bf16 GEMM (small-N lora paths): C = A * B^T ----------------
// EPI: 2 = tanh->f32
template<int EPI>
__global__ __launch_bounds__(256)
void gemm_bt(const unsigned short* __restrict__ Am, const unsigned short* __restrict__ Bm,
             void* __restrict__ Cp, int M, int N, int K) {
  __shared__ unsigned short As[128 * 32];
  __shared__ unsigned short Bs[128 * 32];
  const int tid = threadIdx.x;
  const int wid = tid >> 6, lane = tid & 63;
  const int quad = lane >> 4, l15 = lane & 15;
  const long bm = (long)blockIdx.x * 128, bn = (long)blockIdx.y * 128;
  const int wm = (wid & 1) * 64, wn = (wid >> 1) * 64;

  floatx4 acc[4][4];
#pragma unroll
  for (int a = 0; a < 4; a++)
#pragma unroll
    for (int b = 0; b < 4; b++) { floatx4 z = {0.f, 0.f, 0.f, 0.f}; acc[a][b] = z; }

  const int stg_row = wid * 32 + (lane >> 2);
  const int stg_k   = (lane & 3) * 8;
  const int stg_lds = wid * 1024 + lane * 8;

  for (int k0 = 0; k0 < K; k0 += 32) {
    __syncthreads();
#pragma unroll
    for (int p = 0; p < 2; ++p) {
      gll16(Am + (bm + stg_row + p * 16) * (long)K + k0 + stg_k, &As[stg_lds + p * 512]);
      gll16(Bm + (bn + stg_row + p * 16) * (long)K + k0 + stg_k, &Bs[stg_lds + p * 512]);
    }
    __syncthreads();

    short8 af[4], bfr[4];
#pragma unroll
    for (int mi = 0; mi < 4; mi++) af[mi] = *(const short8*)&As[(wm + mi * 16 + l15) * 32 + quad * 8];
#pragma unroll
    for (int ni = 0; ni < 4; ni++) bfr[ni] = *(const short8*)&Bs[(wn + ni * 16 + l15) * 32 + quad * 8];
#pragma unroll
    for (int mi = 0; mi < 4; mi++)
#pragma unroll
      for (int ni = 0; ni < 4; ni++)
        acc[mi][ni] = __builtin_amdgcn_mfma_f32_16x16x32_bf16(af[mi], bfr[ni], acc[mi][ni], 0, 0, 0);
  }

#pragma unroll
  for (int mi = 0; mi < 4; mi++)
#pragma unroll
    for (int ni = 0; ni < 4; ni++)
#pragma unroll
      for (int vv = 0; vv < 4; ++vv) {
        long row = bm + wm + mi * 16 + quad * 4 + vv;
        long col = bn + wn + ni * 16 + l15;
        float val = acc[mi][ni][vv];
        if (EPI == 2) ((float*)Cp)[row * N + col] = tanhf(val);
      }
}

// ---------------- split-B GEMM: C = A * (Bh+Bl)^T  (weight-exact) ----------------
// EPI: 0 = ->bf16, 1 = silu->bf16, 3 = ->f32
template<int EPI>
__global__ __launch_bounds__(256)
void gemm_sb(const unsigned short* __restrict__ Am, const unsigned short* __restrict__ Bhm,
             const unsigned short* __restrict__ Blm, void* __restrict__ Cp, int M, int N, int K) {
  __shared__ unsigned short As[128 * 32];
  __shared__ unsigned short Bhs[128 * 32];
  __shared__ unsigned short Bls[128 * 32];
  const int tid = threadIdx.x;
  const int wid = tid >> 6, lane = tid & 63;
  const int quad = lane >> 4, l15 = lane & 15;
  const long bm = (long)blockIdx.x * 128, bn = (long)blockIdx.y * 128;
  const int wm = (wid & 1) * 64, wn = (wid >> 1) * 64;

  floatx4 acc[4][4];
#pragma unroll
  for (int a = 0; a < 4; a++)
#pragma unroll
    for (int b = 0; b < 4; b++) { floatx4 z = {0.f, 0.f, 0.f, 0.f}; acc[a][b] = z; }

  const int stg_row = wid * 32 + (lane >> 2);
  const int stg_k   = (lane & 3) * 8;
  const int stg_lds = wid * 1024 + lane * 8;

  for (int k0 = 0; k0 < K; k0 += 32) {
    __syncthreads();
#pragma unroll
    for (int p = 0; p < 2; ++p) {
      const long rowA = (bm + stg_row + p * 16) * (long)K + k0 + stg_k;
      const long rowB = (bn + stg_row + p * 16) * (long)K + k0 + stg_k;
      gll16(Am  + rowA, &As [stg_lds + p * 512]);
      gll16(Bhm + rowB, &Bhs[stg_lds + p * 512]);
      gll16(Blm + rowB, &Bls[stg_lds + p * 512]);
    }
    __syncthreads();

    short8 af[4], bh[4], bl[4];
#pragma unroll
    for (int mi = 0; mi < 4; mi++) af[mi] = *(const short8*)&As[(wm + mi * 16 + l15) * 32 + quad * 8];
#pragma unroll
    for (int ni = 0; ni < 4; ni++) {
      bh[ni] = *(const short8*)&Bhs[(wn + ni * 16 + l15) * 32 + quad * 8];
      bl[ni] = *(const short8*)&Bls[(wn + ni * 16 + l15) * 32 + quad * 8];
    }
#pragma unroll
    for (int mi = 0; mi < 4; mi++)
#pragma unroll
      for (int ni = 0; ni < 4; ni++) {
        acc[mi][ni] = __builtin_amdgcn_mfma_f32_16x16x32_bf16(af[mi], bh[ni], acc[mi][ni], 0, 0, 0);
        acc[mi][ni] = __builtin_amdgcn_mfma_f32_16x16x32_bf16(af[mi], bl[ni], acc[mi][ni], 0, 0, 0);
      }
  }

#pragma unroll
  for (int mi = 0; mi < 4; mi++)
#pragma unroll
    for (int ni = 0; ni < 4; ni++)
#pragma unroll
      for (int vv = 0; vv < 4; ++vv) {
        long row = bm + wm + mi * 16 + quad * 4 + vv;
        long col = bn + wn + ni * 16 + l15;
        float val = acc[mi][ni][vv];
        if (EPI == 0) {
          ((unsigned short*)Cp)[row * N + col] = f2bf(val);
        } else if (EPI == 1) {
          float s = val / (1.f + __expf(-val));
          ((unsigned short*)Cp)[row * N + col] = f2bf(s);
        } else {
          ((float*)Cp)[row * N + col] = val;
        }
      }
}

// ---------------- 3-term GEMM: C = Ah*Bh^T + Ah*Bl^T + Al*Bh^T -> f32 (final proj) ----------------
__global__ __launch_bounds__(256)
void gemm_s3(const unsigned short* __restrict__ Ahm, const unsigned short* __restrict__ Alm,
             const unsigned short* __restrict__ Bhm, const unsigned short* __restrict__ Blm,
             float* __restrict__ Cp, int M, int N, int K) {
  __shared__ unsigned short Ahs[128 * 32];
  __shared__ unsigned short Als[128 * 32];
  __shared__ unsigned short Bhs[128 * 32];
  __shared__ unsigned short Bls[128 * 32];
  const int tid = threadIdx.x;
  const int wid = tid >> 6, lane = tid & 63;
  const int quad = lane >> 4, l15 = lane & 15;
  const long bm = (long)blockIdx.x * 128, bn = (long)blockIdx.y * 128;
  const int wm = (wid & 1) * 64, wn = (wid >> 1) * 64;

  floatx4 acc[4][4];
#pragma unroll
  for (int a = 0; a < 4; a++)
#pragma unroll
    for (int b = 0; b < 4; b++) { floatx4 z = {0.f, 0.f, 0.f, 0.f}; acc[a][b] = z; }

  const int stg_row = wid * 32 + (lane >> 2);
  const int stg_k   = (lane & 3) * 8;
  const int stg_lds = wid * 1024 + lane * 8;

  for (int k0 = 0; k0 < K; k0 += 32) {
    __syncthreads();
#pragma unroll
    for (int p = 0; p < 2; ++p) {
      const long rowA = (bm + stg_row + p * 16) * (long)K + k0 + stg_k;
      const long rowB = (bn + stg_row + p * 16) * (long)K + k0 + stg_k;
      gll16(Ahm + rowA, &Ahs[stg_lds + p * 512]);
      gll16(Alm + rowA, &Als[stg_lds + p * 512]);
      gll16(Bhm + rowB, &Bhs[stg_lds + p * 512]);
      gll16(Blm + rowB, &Bls[stg_lds + p * 512]);
    }
    __syncthreads();

    short8 ah[4], al[4], bh[4], bl[4];
#pragma unroll
    for (int mi = 0; mi < 4; mi++) {
      ah[mi] = *(const short8*)&Ahs[(wm + mi * 16 + l15) * 32 + quad * 8];
      al[mi] = *(const short8*)&Als[(wm + mi * 16 + l15) * 32 + quad * 8];
    }
#pragma unroll
    for (int ni = 0; ni < 4; ni++) {
      bh[ni] = *(const short8*)&Bhs[(wn + ni * 16 + l15) * 32 + quad * 8];
      bl[ni] = *(const short8*)&Bls[(wn + ni * 16 + l15) * 32 + quad * 8];
    }
#pragma unroll
    for (int mi = 0; mi < 4; mi++)
#pragma unroll
      for (int ni = 0; ni < 4; ni++) {
        acc[mi][ni] = __builtin_amdgcn_mfma_f32_16x16x32_bf16(ah[mi], bh[ni], acc[mi][ni], 0, 0, 0);
        acc[mi][ni] = __builtin_amdgcn_mfma_f32_16x16x32_bf16(ah[mi], bl[ni], acc[mi][ni], 0, 0, 0);
        acc[mi][ni] = __builtin_amdgcn_mfma_f32_16x16x32_bf16(al[mi], bh[ni], acc[mi][ni], 0, 0, 0);
      }
  }

#pragma unroll
  for (int mi = 0; mi < 4; mi++)
#pragma unroll
    for (int ni = 0; ni < 4; ni++)
#pragma unroll
      for (int vv = 0; vv < 4; ++vv) {
        long row = bm + wm + mi * 16 + quad * 4 + vv;
        long col = bn + wn + ni * 16 + l15;
        Cp[row * N + col] = acc[mi][ni][vv];
      }
}

// ---------------- fused LoRA-mix (xx recomputed inline) ----------------
__global__ __launch_bounds__(256)
void mix_lora(const float* __restrict__ x,
              const float* __restrict__ m5, const float* __restrict__ w2,
              const float* __restrict__ tmw, const float* __restrict__ tmk,
              const float* __restrict__ tmv, const float* __restrict__ tmr,
              const float* __restrict__ tmg,
              unsigned short* __restrict__ xw, unsigned short* __restrict__ xk,
              unsigned short* __restrict__ xv, unsigned short* __restrict__ xr,
              unsigned short* __restrict__ xg) {
  const int bt0 = blockIdx.x * 16;
  const int tid = threadIdx.x;
  const float* tms[5] = {tmw, tmk, tmv, tmr, tmg};
  unsigned short* outs[5] = {xw, xk, xv, xr, xg};
  for (int cc = 0; cc < 8; ++cc) {
    const int c = cc * 256 + tid;
    float xv_[16], xxv_[16];
#pragma unroll
    for (int b = 0; b < 16; b++) {
      const int bt = bt0 + b;
      size_t idx = ((size_t)bt << 11) + c;
      float xc = x[idx];
      float xp = ((bt & 2047) > 0) ? x[idx - 2048] : 0.f;
      xv_[b] = xc; xxv_[b] = xp - xc;
    }
#pragma unroll
    for (int f = 0; f < 5; ++f) {
      const float tmf = tms[f][c];
      float acc[16];
#pragma unroll
      for (int b = 0; b < 16; b++) acc[b] = 0.f;
      for (int dc = 0; dc < 8; ++dc) {
        float wv0 = w2[((size_t)(f * 32 + dc * 4 + 0) << 11) + c];
        float wv1 = w2[((size_t)(f * 32 + dc * 4 + 1) << 11) + c];
        float wv2 = w2[((size_t)(f * 32 + dc * 4 + 2) << 11) + c];
        float wv3 = w2[((size_t)(f * 32 + dc * 4 + 3) << 11) + c];
#pragma unroll
        for (int b = 0; b < 16; b++) {
          float4 mv = *(const float4*)&m5[((size_t)(bt0 + b) << 8) + f * 32 + dc * 4];
          acc[b] += mv.x * wv0 + mv.y * wv1 + mv.z * wv2 + mv.w * wv3;
        }
      }
#pragma unroll
      for (int b = 0; b < 16; b++) {
        size_t idx = ((size_t)(bt0 + b) << 11) + c;
        outs[f][idx] = f2bf(xv_[b] + xxv_[b] * (tmf + acc[b]));
      }
    }
  }
}

// ---------------- decay: dec = exp(-exp(td + t1 @ decay_w2)) (f32) ----------------
__global__ __launch_bounds__(256)
void decay_kernel(const float* __restrict__ t1, const float* __restrict__ w2d,
                  const float* __restrict__ td, float* __restrict__ dec) {
  const int bt0 = blockIdx.x * 16;
  const int tid = threadIdx.x;
  for (int cc = 0; cc < 8; ++cc) {
    const int a = cc * 256 + tid;
    const float tda = td[a];
    float acc[16];
#pragma unroll
    for (int b = 0; b < 16; b++) acc[b] = 0.f;
    for (int dc = 0; dc < 16; ++dc) {
      float wv0 = w2d[((size_t)(dc * 4 + 0) << 11) + a];
      float wv1 = w2d[((size_t)(dc * 4 + 1) << 11) + a];
      float wv2 = w2d[((size_t)(dc * 4 + 2) << 11) + a];
      float wv3 = w2d[((size_t)(dc * 4 + 3) << 11) + a];
#pragma unroll
      for (int b = 0; b < 16; b++) {
        float4 mv = *(const float4*)&t1[((size_t)(bt0 + b) << 7) + dc * 4];
        acc[b] += mv.x * wv0 + mv.y * wv1 + mv.z * wv2 + mv.w * wv3;
      }
    }
#pragma unroll
    for (int b = 0; b < 16; b++) {
      dec[((size_t)(bt0 + b) << 11) + a] = __expf(-__expf(tda + acc[b]));
    }
  }
}

// ---------------- WKV6 chunk-parallel (MFMA) + fused GroupNorm*g ----------------
// block = one (b,h), 256 threads = 4 waves. Chunk L=64 over T.
// Exact reformulation with local cumprod Lc_t = prod_{tau<=t} d_tau, Pl_t = Lc_{t-1}:
//   R~ = r .* Pl ; K~ = k ./ Lc
//   A[t][s] = R~_t . K~_s  (s<t) ;  A[t][t] = r_t.(u.*k_t) ;  A[t][s>t]=0
//   y = A V + R~ S0 ;  S_next = Lc_63 .*rows ( K~^T V + S0 )
// All matmuls are C = X * Y^T (both operands row-major [.][K]) via
// mfma_f32_16x16x32_bf16 with hi/lo bf16 splits (3 combos) for f32-level accuracy.
// LDS tiles XOR-swizzled (col ^= (row&7)<<3) per G4 to kill ds_read_b128 conflicts.
// GroupNorm*g fused in-register (wave owns whole rows) -> z_hi over g, z_lo over r.
template<int KF32>
__global__ __launch_bounds__(256, 1)
void wkv6_chunk(const unsigned short* __restrict__ r, const unsigned short* __restrict__ k16,
                const float* __restrict__ k32, const float* __restrict__ v,
                const float* __restrict__ dec, const float* __restrict__ u,
                unsigned short* __restrict__ gz, unsigned short* __restrict__ zlo,
                const float* __restrict__ lnw, const float* __restrict__ lnb) {
  __shared__ unsigned short Rh[4096], Rl[4096];     // R~ [t][i]
  __shared__ unsigned short Kh[4096], Kl[4096];     // K~ [s][i]
  __shared__ unsigned short KTh[4096], KTl[4096];   // K~^T [i][s]
  __shared__ unsigned short VTh[4096], VTl[4096];   // V^T [j][s]
  __shared__ unsigned short Amh[4096], Aml[4096];   // masked A [t][s]
  __shared__ unsigned short SThi[4096], STlo[4096]; // S^T bf16 [j][i]
  __shared__ float STf[4096];                       // S^T f32 [j][i] (persistent)
  __shared__ float qpart[4][64];
  __shared__ float LcEnd[64];
  __shared__ float diagv[64];

  const int bh = blockIdx.x, b = bh >> 5, h = bh & 31;
  const int tid = threadIdx.x;
  const int w = tid >> 6, lane = tid & 63;
  const int quad = lane >> 4, l15 = lane & 15;
  const int cb = h * 64;
  const int tq = w * 16;            // this wave's row quarter (t / j rows)

  const float uu = u[cb + lane];
  float lnwv[4], lnbv[4];
#pragma unroll
  for (int ni = 0; ni < 4; ++ni) {
    lnwv[ni] = lnw[cb + ni * 16 + l15];
    lnbv[ni] = lnb[cb + ni * 16 + l15];
  }

  for (int i = tid; i < 4096; i += 256) STf[i] = 0.f;

  const size_t bT = (size_t)b * T_;

  for (int c = 0; c < T_ / 64; ++c) {
    const int t0 = c * 64;
    // ---------- phase 1a: load chunk rows, local cumprod ----------
    float d_[16], r_[16], k_[16], v_[16], lcq[16];
    {
      const size_t ro = (bT + t0 + tq) * (size_t)A_ + cb + lane;
#pragma unroll
      for (int q = 0; q < 16; ++q) {
        const size_t o = ro + (size_t)q * A_;
        d_[q] = dec[o];
        r_[q] = bf2f(r[o]);
        if (KF32) k_[q] = k32[o];
        else      k_[q] = bf2f(k16[o]);
        v_[q] = v[o];
      }
      lcq[0] = d_[0];
#pragma unroll
      for (int q = 1; q < 16; ++q) lcq[q] = lcq[q - 1] * d_[q];
      qpart[w][lane] = lcq[15];
    }
    __syncthreads();
    // ---------- phase 1b: build operands ----------
    {
      float pre = 1.f;
      if (w > 0) pre *= qpart[0][lane];
      if (w > 1) pre *= qpart[1][lane];
      if (w > 2) pre *= qpart[2][lane];
      if (w == 3) LcEnd[lane] = pre * lcq[15];
      unsigned short hh, ll;
#pragma unroll
      for (int q = 0; q < 16; ++q) {
        const int jr = tq + q;
        split_hl(STf[jr * 64 + lane], hh, ll);
        const int ixs = swz(jr, lane);
        SThi[ixs] = hh; STlo[ixs] = ll;
      }
#pragma unroll
      for (int q = 0; q < 16; ++q) {
        const int tr = tq + q;
        const float Pl = q ? pre * lcq[q - 1] : pre;
        const float Lc = pre * lcq[q];
        const int ix = swz(tr, lane);
        const int ixT = swz(lane, tr);
        split_hl(r_[q] * Pl, hh, ll);
        Rh[ix] = hh; Rl[ix] = ll;
        const float kn = k_[q] / Lc;
        split_hl(kn, hh, ll);
        Kh[ix] = hh; Kl[ix] = ll;
        KTh[ixT] = hh; KTl[ixT] = ll;
        split_hl(v_[q], hh, ll);
        VTh[ixT] = hh; VTl[ixT] = ll;
        float dp = r_[q] * uu * k_[q];
        dp += __shfl_xor(dp, 1, 64);
        dp += __shfl_xor(dp, 2, 64);
        dp += __shfl_xor(dp, 4, 64);
        dp += __shfl_xor(dp, 8, 64);
        dp += __shfl_xor(dp, 16, 64);
        dp += __shfl_xor(dp, 32, 64);
        if (lane == 0) diagv[tr] = dp;
      }
    }
    __syncthreads();
    // ---------- phase 2: A = R~ K~^T, mask, store hi/lo ----------
    {
      short8 arh[2], arl[2];
#pragma unroll
      for (int kst = 0; kst < 2; ++kst) {
        const int c8 = kst * 32 + quad * 8;
        arh[kst] = ldfrag(Rh, tq + l15, c8);
        arl[kst] = ldfrag(Rl, tq + l15, c8);
      }
      floatx4 acc[4];
#pragma unroll
      for (int ni = 0; ni < 4; ++ni) { floatx4 z = {0.f, 0.f, 0.f, 0.f}; acc[ni] = z; }
#pragma unroll
      for (int ni = 0; ni < 4; ++ni)
#pragma unroll
        for (int kst = 0; kst < 2; ++kst) {
          const int c8 = kst * 32 + quad * 8;
          short8 bh_ = ldfrag(Kh, ni * 16 + l15, c8);
          short8 bl_ = ldfrag(Kl, ni * 16 + l15, c8);
          acc[ni] = __builtin_amdgcn_mfma_f32_16x16x32_bf16(arh[kst], bh_, acc[ni], 0, 0, 0);
          acc[ni] = __builtin_amdgcn_mfma_f32_16x16x32_bf16(arh[kst], bl_, acc[ni], 0, 0, 0);
          acc[ni] = __builtin_amdgcn_mfma_f32_16x16x32_bf16(arl[kst], bh_, acc[ni], 0, 0, 0);
        }
#pragma unroll
      for (int ni = 0; ni < 4; ++ni)
#pragma unroll
        for (int vv = 0; vv < 4; ++vv) {
          const int grow = tq + quad * 4 + vv;
          const int gcol = ni * 16 + l15;
          float val = (grow > gcol) ? acc[ni][vv] : ((grow == gcol) ? diagv[grow] : 0.f);
          unsigned short hh, ll;
          split_hl(val, hh, ll);
          const int ix = swz(grow, gcol);
          Amh[ix] = hh; Aml[ix] = ll;
        }
    }
    __syncthreads();
    // ---------- phase 3: Y = A V + R~ S0^T^T, GN*g epilogue ----------
    {
      short8 aAh[2], aAl[2], aRh[2], aRl[2];
#pragma unroll
      for (int kst = 0; kst < 2; ++kst) {
        const int c8 = kst * 32 + quad * 8;
        aAh[kst] = ldfrag(Amh, tq + l15, c8);
        aAl[kst] = ldfrag(Aml, tq + l15, c8);
        aRh[kst] = ldfrag(Rh, tq + l15, c8);
        aRl[kst] = ldfrag(Rl, tq + l15, c8);
      }
      floatx4 acc[4];
#pragma unroll
      for (int ni = 0; ni < 4; ++ni) { floatx4 z = {0.f, 0.f, 0.f, 0.f}; acc[ni] = z; }
#pragma unroll
      for (int ni = 0; ni < 4; ++ni)
#pragma unroll
        for (int kst = 0; kst < 2; ++kst) {
          const int c8 = kst * 32 + quad * 8;
          short8 bvh = ldfrag(VTh, ni * 16 + l15, c8);
          short8 bvl = ldfrag(VTl, ni * 16 + l15, c8);
          acc[ni] = __builtin_amdgcn_mfma_f32_16x16x32_bf16(aAh[kst], bvh, acc[ni], 0, 0, 0);
          acc[ni] = __builtin_amdgcn_mfma_f32_16x16x32_bf16(aAh[kst], bvl, acc[ni], 0, 0, 0);
          acc[ni] = __builtin_amdgcn_mfma_f32_16x16x32_bf16(aAl[kst], bvh, acc[ni], 0, 0, 0);
          short8 bsh = ldfrag(SThi, ni * 16 + l15, c8);
          short8 bsl = ldfrag(STlo, ni * 16 + l15, c8);
          acc[ni] = __builtin_amdgcn_mfma_f32_16x16x32_bf16(aRh[kst], bsh, acc[ni], 0, 0, 0);
          acc[ni] = __builtin_amdgcn_mfma_f32_16x16x32_bf16(aRh[kst], bsl, acc[ni], 0, 0, 0);
          acc[ni] = __builtin_amdgcn_mfma_f32_16x16x32_bf16(aRl[kst], bsh, acc[ni], 0, 0, 0);
        }
      // GroupNorm stats per row (over all 64 cols: 4 ni partial + 16-lane group reduce)
      float mu_[4], rs_[4];
#pragma unroll
      for (int vv = 0; vv < 4; ++vv) {
        float s1 = acc[0][vv] + acc[1][vv] + acc[2][vv] + acc[3][vv];
        float s2 = acc[0][vv] * acc[0][vv] + acc[1][vv] * acc[1][vv]
                 + acc[2][vv] * acc[2][vv] + acc[3][vv] * acc[3][vv];
        s1 += __shfl_xor(s1, 1, 64); s2 += __shfl_xor(s2, 1, 64);
        s1 += __shfl_xor(s1, 2, 64); s2 += __shfl_xor(s2, 2, 64);
        s1 += __shfl_xor(s1, 4, 64); s2 += __shfl_xor(s2, 4, 64);
        s1 += __shfl_xor(s1, 8, 64); s2 += __shfl_xor(s2, 8, 64);
        float mu = s1 * (1.f / 64.f);
        float var = s2 * (1.f / 64.f) - mu * mu;
        mu_[vv] = mu;
        rs_[vv] = rsqrtf(var + 6.4e-4f);   // EPS = 1e-5 * 64
      }
#pragma unroll
      for (int ni = 0; ni < 4; ++ni)
#pragma unroll
        for (int vv = 0; vv < 4; ++vv) {
          const size_t off = (bT + t0 + tq + quad * 4 + vv) * (size_t)A_ + cb + ni * 16 + l15;
          float yn = (acc[ni][vv] - mu_[vv]) * rs_[vv] * lnwv[ni] + lnbv[ni];
          float z = yn * bf2f(gz[off]);
          unsigned short zh = f2bf(z);
          gz[off] = zh;
          zlo[off] = f2bf(z - bf2f(zh));
        }
    }
    // ---------- phase 4: S^T = LcEnd .*cols ( V^T K~ + S^T ) ----------
    // (no barrier needed vs phase 3: ph3 reads SThi/STlo bf16 copies, not STf)
    {
      short8 avh[2], avl[2];
#pragma unroll
      for (int kst = 0; kst < 2; ++kst) {
        const int c8 = kst * 32 + quad * 8;
        avh[kst] = ldfrag(VTh, tq + l15, c8);
        avl[kst] = ldfrag(VTl, tq + l15, c8);
      }
      floatx4 a4[4];
#pragma unroll
      for (int ni = 0; ni < 4; ++ni) { floatx4 z = {0.f, 0.f, 0.f, 0.f}; a4[ni] = z; }
#pragma unroll
      for (int ni = 0; ni < 4; ++ni)
#pragma unroll
        for (int kst = 0; kst < 2; ++kst) {
          const int c8 = kst * 32 + quad * 8;
          short8 bkh = ldfrag(KTh, ni * 16 + l15, c8);
          short8 bkl = ldfrag(KTl, ni * 16 + l15, c8);
          a4[ni] = __builtin_amdgcn_mfma_f32_16x16x32_bf16(avh[kst], bkh, a4[ni], 0, 0, 0);
          a4[ni] = __builtin_amdgcn_mfma_f32_16x16x32_bf16(avh[kst], bkl, a4[ni], 0, 0, 0);
          a4[ni] = __builtin_amdgcn_mfma_f32_16x16x32_bf16(avl[kst], bkh, a4[ni], 0, 0, 0);
        }
#pragma unroll
      for (int ni = 0; ni < 4; ++ni)
#pragma unroll
        for (int vv = 0; vv < 4; ++vv) {
          const int jr = tq + quad * 4 + vv;
          const int ic = ni * 16 + l15;
          STf[jr * 64 + ic] = LcEnd[ic] * (a4[ni][vv] + STf[jr * 64 + ic]);
        }
    }
    __syncthreads();   // STf/operand tiles stable before next chunk's phase 1
  }
}

// ---------------- launch ----------------
extern "C" void kernel_launch(void* const* d_in, const int* in_sizes, int n_in,
                              void* d_out, int out_size, void* d_ws, size_t ws_size,
                              hipStream_t stream) {
  (void)in_sizes; (void)n_in; (void)out_size;
  const float* x   = (const float*)d_in[0];
  const float* tmx = (const float*)d_in[1];
  const float* tmw = (const float*)d_in[2];
  const float* tmk = (const float*)d_in[3];
  const float* tmv = (const float*)d_in[4];
  const float* tmr = (const float*)d_in[5];
  const float* tmg = (const float*)d_in[6];
  const float* w1  = (const float*)d_in[7];   // (C,160)
  const float* w2  = (const float*)d_in[8];   // (5,32,C)
  const float* td  = (const float*)d_in[9];   // (A)
  const float* dw1 = (const float*)d_in[10];  // (C,64)
  const float* dw2 = (const float*)d_in[11];  // (64,A)
  const float* u   = (const float*)d_in[12];  // (H,N)
  const float* Wr  = (const float*)d_in[13];
  const float* Wk  = (const float*)d_in[14];
  const float* Wv  = (const float*)d_in[15];
  const float* Wg  = (const float*)d_in[16];
  const float* Wo  = (const float*)d_in[17];
  const float* lnw = (const float*)d_in[18];
  const float* lnb = (const float*)d_in[19];

  char* ws = (char*)d_ws;
  const size_t MB = 1024 * 1024;
  // 472MB layout (proven safe footprint), lifetime-overlapped:
  // [0,64)    U0: xxx -> g -> z_hi (in place)
  // [64,80)       m5 (f32, 16MB) -> later v-f32 lower half spans [64,128)
  // [128,192) U2: bxk (w1T scratch at [128,129) pre-mix) -> v-f32 upper half
  // [192,256) U3: bxv -> dec lower half
  // [256,320) U4: bxw -> dec upper half     (dec = [192,320) f32, read-only in chunk kernel)
  // [320,384) U5: bxg -> r -> z_lo overlay (chunk kernel)
  // [384,448) U6: bxr -> k (bf16, L0)
  // [448,464)     W_hi/W_lo scratch (dw1T pre) -> W_hi/W_lo (Wo)
  // [464,472)     t1 (f32, 8MB)
  unsigned short* xxx  = (unsigned short*)(ws + 0 * MB);
  unsigned short* gb   = (unsigned short*)(ws + 0 * MB);     // z_hi
  float*          m5   = (float*)(ws + 64 * MB);
  float*          vf   = (float*)(ws + 64 * MB);             // v f32 [64,192)
  unsigned short* w1T  = (unsigned short*)(ws + 128 * MB);
  unsigned short* bxk  = (unsigned short*)(ws + 128 * MB);
  unsigned short* bxv  = (unsigned short*)(ws + 192 * MB);
  float*          decb = (float*)(ws + 192 * MB);            // dec f32 [192,320)
  unsigned short* bxw  = (unsigned short*)(ws + 256 * MB);
  unsigned short* bxg  = (unsigned short*)(ws + 320 * MB);
  unsigned short* rb   = (unsigned short*)(ws + 320 * MB);   // r, then z_lo overlay
  unsigned short* bxr  = (unsigned short*)(ws + 384 * MB);
  unsigned short* kb   = (unsigned short*)(ws + 384 * MB);   // k bf16 (L0)
  unsigned short* dw1T = (unsigned short*)(ws + 448 * MB);
  unsigned short* Whi  = (unsigned short*)(ws + 448 * MB);
  unsigned short* Wlo  = (unsigned short*)(ws + 456 * MB);
  float*          t1   = (float*)(ws + 464 * MB);
  // optional upgrade: k in f32 at [480,608) if workspace allows (runtime-constant branch)
  const bool kf32 = ws_size >= (size_t)616 * MB;
  float* kf = (float*)(ws + 480 * MB);

  const int nW = A_ * C_;  // 4.19M elements
  const size_t EBT = (size_t)BT_ * C_;

  // 1. token-shift mix -> xxx
  shift_mix<<<(int)(EBT / 4 / 256), 256, 0, stream>>>(x, tmx, xxx);

  // 2. m5 = tanh(xxx @ maa_w1) padded N=256
  transpose_pad<<<(256 * 2048) / 256, 256, 0, stream>>>(w1, w1T, 256, 160);
  gemm_bt<2><<<dim3(BT_ / 128, 2), 256, 0, stream>>>(xxx, w1T, m5, BT_, 256, 2048);

  // 3. five mixed inputs
  mix_lora<<<BT_ / 16, 256, 0, stream>>>(x, m5, w2, tmw, tmk, tmv, tmr, tmg,
                                         bxw, bxk, bxv, bxr, bxg);

  // 4. t1 = tanh(xw @ decay_w1) padded N=128
  transpose_pad<<<(128 * 2048) / 256, 256, 0, stream>>>(dw1, dw1T, 128, 64);
  gemm_bt<2><<<dim3(BT_ / 128, 1), 256, 0, stream>>>(bxw, dw1T, t1, BT_, 128, 2048);

  // 5-8. projections with split-exact weights (order matters for slot recycling)
  conv_hilo<<<nW / 256, 256, 0, stream>>>(Wg, Whi, Wlo, nW);
  gemm_sb<1><<<dim3(BT_ / 128, 16), 256, 0, stream>>>(bxg, Whi, Wlo, gb, BT_, 2048, 2048);
  conv_hilo<<<nW / 256, 256, 0, stream>>>(Wr, Whi, Wlo, nW);
  gemm_sb<0><<<dim3(BT_ / 128, 16), 256, 0, stream>>>(bxr, Whi, Wlo, rb, BT_, 2048, 2048);
  conv_hilo<<<nW / 256, 256, 0, stream>>>(Wk, Whi, Wlo, nW);
  if (kf32) {
    gemm_sb<3><<<dim3(BT_ / 128, 16), 256, 0, stream>>>(bxk, Whi, Wlo, kf, BT_, 2048, 2048);
  } else {
    gemm_sb<0><<<dim3(BT_ / 128, 16), 256, 0, stream>>>(bxk, Whi, Wlo, kb, BT_, 2048, 2048);
  }
  conv_hilo<<<nW / 256, 256, 0, stream>>>(Wv, Whi, Wlo, nW);
  gemm_sb<3><<<dim3(BT_ / 128, 16), 256, 0, stream>>>(bxv, Whi, Wlo, vf, BT_, 2048, 2048);

  // 9. dec (after bxv/bxw are dead; overlays them)
  decay_kernel<<<BT_ / 16, 256, 0, stream>>>(t1, dw2, td, decb);

  // 10. WKV6 chunk-parallel MFMA + fused GroupNorm*g -> z_hi (over g), z_lo (over r)
  if (kf32) {
    wkv6_chunk<1><<<256, 256, 0, stream>>>(rb, kb, kf, vf, decb, u, gb, rb, lnw, lnb);
  } else {
    wkv6_chunk<0><<<256, 256, 0, stream>>>(rb, kb, kf, vf, decb, u, gb, rb, lnw, lnb);
  }

  // 11. output projection: (z_hi + z_lo) @ (Wo_hi + Wo_lo)^T -> d_out (f32)
  conv_hilo<<<nW / 256, 256, 0, stream>>>(Wo, Whi, Wlo, nW);
  gemm_s3<<<dim3(BT_ / 128, 16), 256, 0, stream>>>(gb, rb, Whi, Wlo, (float*)d_out, BT_, 2048, 2048);
}

// Round 5
// 2833.020 us; speedup vs baseline: 1.2205x; 1.0645x over previous
//
#include <hip/hip_runtime.h>
#include <hip/hip_bf16.h>
#include <cstdint>
#include <cstddef>

#define B_ 8
#define T_ 2048
#define C_ 2048
#define A_ 2048
#define H_ 32
#define BT_ (B_*T_)

typedef short short8 __attribute__((ext_vector_type(8)));
typedef float floatx4 __attribute__((ext_vector_type(4)));

__device__ __forceinline__ unsigned short f2bf(float f) {
  union { float f; uint32_t u; } a; a.f = f;
  uint32_t r = a.u + 0x7fffu + ((a.u >> 16) & 1u);   // RNE
  return (unsigned short)(r >> 16);
}
__device__ __forceinline__ float bf2f(unsigned short s) {
  union { uint32_t u; float f; } a; a.u = ((uint32_t)s) << 16;
  return a.f;
}
__device__ __forceinline__ void split_hl(float v, unsigned short& hh, unsigned short& ll) {
  hh = f2bf(v);
  ll = f2bf(v - bf2f(hh));
}
// XOR-swizzled index into a row-major [64][64] bf16 LDS tile (G4 recipe)
__device__ __forceinline__ int swz(int row, int col) {
  return row * 64 + (col ^ ((row & 7) << 3));
}
__device__ __forceinline__ short8 ldfrag(const unsigned short* M, int row, int col8) {
  return *(const short8*)&M[row * 64 + (col8 ^ ((row & 7) << 3))];
}

// ---------------- weight prep: hi/lo bf16 split ----------------
__global__ void conv_hilo(const float* __restrict__ s, unsigned short* __restrict__ hi,
                          unsigned short* __restrict__ lo, int n) {
  int i = blockIdx.x * 256 + threadIdx.x;
  if (i < n) {
    float v = s[i];
    unsigned short h = f2bf(v);
    hi[i] = h;
    lo[i] = f2bf(v - bf2f(h));
  }
}

// src (2048 x NV) f32 -> dst (NP x 2048) bf16, rows >= NV zero-padded
__global__ void transpose_pad(const float* __restrict__ s, unsigned short* __restrict__ d, int NP, int NV) {
  int i = blockIdx.x * 256 + threadIdx.x;  // over NP*2048
  int n = i >> 11, kk = i & 2047;
  if (n < NP) d[i] = (n < NV) ? f2bf(s[kk * NV + n]) : (unsigned short)0;
}

// ---------------- token shift + maa_x mix ----------------
__global__ void shift_mix(const float* __restrict__ x, const float* __restrict__ tmx,
                          unsigned short* __restrict__ xxx) {
  size_t i4 = (size_t)blockIdx.x * 256 + threadIdx.x;   // over BT*C/4
  size_t i = i4 * 4;
  int c = (int)(i & 2047);
  int t = (int)((i >> 11) & 2047);
  float4 xv = *(const float4*)&x[i];
  float4 pv = make_float4(0.f, 0.f, 0.f, 0.f);
  if (t > 0) pv = *(const float4*)&x[i - 2048];
  float4 tv = *(const float4*)&tmx[c];
  ushort4 m;
  m.x = f2bf(xv.x + (pv.x - xv.x) * tv.x);
  m.y = f2bf(xv.y + (pv.y - xv.y) * tv.y);
  m.z = f2bf(xv.z + (pv.z - xv.z) * tv.z);
  m.w = f2bf(xv.w + (pv.w - xv.w) * tv.w);
  *(ushort4*)&xxx[i] = m;
}

// ---------------- async global->LDS helper ----------------
__device__ __forceinline__ void gll16(const void* g, void* l) {
  __builtin_amdgcn_global_load_lds(
      (const __attribute__((address_space(1))) void*)g,
      (__attribute__((address_space(3))) void*)l, 16, 0, 0);
}

// ---------------- plain bf16 GEMM (small-N lora paths): C = A * B^T ----------------
// EPI: 2 = tanh->f32
template<int EPI>
__global__ __launch_bounds__(256)
void gemm_bt(const unsigned short* __restrict__ Am, const unsigned short* __restrict__ Bm,
             void* __restrict__ Cp, int M, int N, int K) {
  __shared__ unsigned short As[128 * 32];
  __shared__ unsigned short Bs[128 * 32];
  const int tid = threadIdx.x;
  const int wid = tid >> 6, lane = tid & 63;
  const int quad = lane >> 4, l15 = lane & 15;
  const long bm = (long)blockIdx.x * 128, bn = (long)blockIdx.y * 128;
  const int wm = (wid & 1) * 64, wn = (wid >> 1) * 64;

  floatx4 acc[4][4];
#pragma unroll
  for (int a = 0; a < 4; a++)
#pragma unroll
    for (int b = 0; b < 4; b++) { floatx4 z = {0.f, 0.f, 0.f, 0.f}; acc[a][b] = z; }

  const int stg_row = wid * 32 + (lane >> 2);
  const int stg_k   = (lane & 3) * 8;
  const int stg_lds = wid * 1024 + lane * 8;

  for (int k0 = 0; k0 < K; k0 += 32) {
    __syncthreads();
#pragma unroll
    for (int p = 0; p < 2; ++p) {
      gll16(Am + (bm + stg_row + p * 16) * (long)K + k0 + stg_k, &As[stg_lds + p * 512]);
      gll16(Bm + (bn + stg_row + p * 16) * (long)K + k0 + stg_k, &Bs[stg_lds + p * 512]);
    }
    __syncthreads();

    short8 af[4], bfr[4];
#pragma unroll
    for (int mi = 0; mi < 4; mi++) af[mi] = *(const short8*)&As[(wm + mi * 16 + l15) * 32 + quad * 8];
#pragma unroll
    for (int ni = 0; ni < 4; ni++) bfr[ni] = *(const short8*)&Bs[(wn + ni * 16 + l15) * 32 + quad * 8];
#pragma unroll
    for (int mi = 0; mi < 4; mi++)
#pragma unroll
      for (int ni = 0; ni < 4; ni++)
        acc[mi][ni] = __builtin_amdgcn_mfma_f32_16x16x32_bf16(af[mi], bfr[ni], acc[mi][ni], 0, 0, 0);
  }

#pragma unroll
  for (int mi = 0; mi < 4; mi++)
#pragma unroll
    for (int ni = 0; ni < 4; ni++)
#pragma unroll
      for (int vv = 0; vv < 4; ++vv) {
        long row = bm + wm + mi * 16 + quad * 4 + vv;
        long col = bn + wn + ni * 16 + l15;
        float val = acc[mi][ni][vv];
        if (EPI == 2) ((float*)Cp)[row * N + col] = tanhf(val);
      }
}

// ---------------- split-B GEMM: C = A * (Bh+Bl)^T  (weight-exact) ----------------
// EPI: 0 = ->bf16, 1 = silu->bf16, 3 = ->f32
template<int EPI>
__global__ __launch_bounds__(256)
void gemm_sb(const unsigned short* __restrict__ Am, const unsigned short* __restrict__ Bhm,
             const unsigned short* __restrict__ Blm, void* __restrict__ Cp, int M, int N, int K) {
  __shared__ unsigned short As[128 * 32];
  __shared__ unsigned short Bhs[128 * 32];
  __shared__ unsigned short Bls[128 * 32];
  const int tid = threadIdx.x;
  const int wid = tid >> 6, lane = tid & 63;
  const int quad = lane >> 4, l15 = lane & 15;
  const long bm = (long)blockIdx.x * 128, bn = (long)blockIdx.y * 128;
  const int wm = (wid & 1) * 64, wn = (wid >> 1) * 64;

  floatx4 acc[4][4];
#pragma unroll
  for (int a = 0; a < 4; a++)
#pragma unroll
    for (int b = 0; b < 4; b++) { floatx4 z = {0.f, 0.f, 0.f, 0.f}; acc[a][b] = z; }

  const int stg_row = wid * 32 + (lane >> 2);
  const int stg_k   = (lane & 3) * 8;
  const int stg_lds = wid * 1024 + lane * 8;

  for (int k0 = 0; k0 < K; k0 += 32) {
    __syncthreads();
#pragma unroll
    for (int p = 0; p < 2; ++p) {
      const long rowA = (bm + stg_row + p * 16) * (long)K + k0 + stg_k;
      const long rowB = (bn + stg_row + p * 16) * (long)K + k0 + stg_k;
      gll16(Am  + rowA, &As [stg_lds + p * 512]);
      gll16(Bhm + rowB, &Bhs[stg_lds + p * 512]);
      gll16(Blm + rowB, &Bls[stg_lds + p * 512]);
    }
    __syncthreads();

    short8 af[4], bh[4], bl[4];
#pragma unroll
    for (int mi = 0; mi < 4; mi++) af[mi] = *(const short8*)&As[(wm + mi * 16 + l15) * 32 + quad * 8];
#pragma unroll
    for (int ni = 0; ni < 4; ni++) {
      bh[ni] = *(const short8*)&Bhs[(wn + ni * 16 + l15) * 32 + quad * 8];
      bl[ni] = *(const short8*)&Bls[(wn + ni * 16 + l15) * 32 + quad * 8];
    }
#pragma unroll
    for (int mi = 0; mi < 4; mi++)
#pragma unroll
      for (int ni = 0; ni < 4; ni++) {
        acc[mi][ni] = __builtin_amdgcn_mfma_f32_16x16x32_bf16(af[mi], bh[ni], acc[mi][ni], 0, 0, 0);
        acc[mi][ni] = __builtin_amdgcn_mfma_f32_16x16x32_bf16(af[mi], bl[ni], acc[mi][ni], 0, 0, 0);
      }
  }

#pragma unroll
  for (int mi = 0; mi < 4; mi++)
#pragma unroll
    for (int ni = 0; ni < 4; ni++)
#pragma unroll
      for (int vv = 0; vv < 4; ++vv) {
        long row = bm + wm + mi * 16 + quad * 4 + vv;
        long col = bn + wn + ni * 16 + l15;
        float val = acc[mi][ni][vv];
        if (EPI == 0) {
          ((unsigned short*)Cp)[row * N + col] = f2bf(val);
        } else if (EPI == 1) {
          float s = val / (1.f + __expf(-val));
          ((unsigned short*)Cp)[row * N + col] = f2bf(s);
        } else {
          ((float*)Cp)[row * N + col] = val;
        }
      }
}

// ---------------- 3-term GEMM: C = Ah*Bh^T + Ah*Bl^T + Al*Bh^T -> f32 (final proj) ----------------
__global__ __launch_bounds__(256)
void gemm_s3(const unsigned short* __restrict__ Ahm, const unsigned short* __restrict__ Alm,
             const unsigned short* __restrict__ Bhm, const unsigned short* __restrict__ Blm,
             float* __restrict__ Cp, int M, int N, int K) {
  __shared__ unsigned short Ahs[128 * 32];
  __shared__ unsigned short Als[128 * 32];
  __shared__ unsigned short Bhs[128 * 32];
  __shared__ unsigned short Bls[128 * 32];
  const int tid = threadIdx.x;
  const int wid = tid >> 6, lane = tid & 63;
  const int quad = lane >> 4, l15 = lane & 15;
  const long bm = (long)blockIdx.x * 128, bn = (long)blockIdx.y * 128;
  const int wm = (wid & 1) * 64, wn = (wid >> 1) * 64;

  floatx4 acc[4][4];
#pragma unroll
  for (int a = 0; a < 4; a++)
#pragma unroll
    for (int b = 0; b < 4; b++) { floatx4 z = {0.f, 0.f, 0.f, 0.f}; acc[a][b] = z; }

  const int stg_row = wid * 32 + (lane >> 2);
  const int stg_k   = (lane & 3) * 8;
  const int stg_lds = wid * 1024 + lane * 8;

  for (int k0 = 0; k0 < K; k0 += 32) {
    __syncthreads();
#pragma unroll
    for (int p = 0; p < 2; ++p) {
      const long rowA = (bm + stg_row + p * 16) * (long)K + k0 + stg_k;
      const long rowB = (bn + stg_row + p * 16) * (long)K + k0 + stg_k;
      gll16(Ahm + rowA, &Ahs[stg_lds + p * 512]);
      gll16(Alm + rowA, &Als[stg_lds + p * 512]);
      gll16(Bhm + rowB, &Bhs[stg_lds + p * 512]);
      gll16(Blm + rowB, &Bls[stg_lds + p * 512]);
    }
    __syncthreads();

    short8 ah[4], al[4], bh[4], bl[4];
#pragma unroll
    for (int mi = 0; mi < 4; mi++) {
      ah[mi] = *(const short8*)&Ahs[(wm + mi * 16 + l15) * 32 + quad * 8];
      al[mi] = *(const short8*)&Als[(wm + mi * 16 + l15) * 32 + quad * 8];
    }
#pragma unroll
    for (int ni = 0; ni < 4; ni++) {
      bh[ni] = *(const short8*)&Bhs[(wn + ni * 16 + l15) * 32 + quad * 8];
      bl[ni] = *(const short8*)&Bls[(wn + ni * 16 + l15) * 32 + quad * 8];
    }
#pragma unroll
    for (int mi = 0; mi < 4; mi++)
#pragma unroll
      for (int ni = 0; ni < 4; ni++) {
        acc[mi][ni] = __builtin_amdgcn_mfma_f32_16x16x32_bf16(ah[mi], bh[ni], acc[mi][ni], 0, 0, 0);
        acc[mi][ni] = __builtin_amdgcn_mfma_f32_16x16x32_bf16(ah[mi], bl[ni], acc[mi][ni], 0, 0, 0);
        acc[mi][ni] = __builtin_amdgcn_mfma_f32_16x16x32_bf16(al[mi], bh[ni], acc[mi][ni], 0, 0, 0);
      }
  }

#pragma unroll
  for (int mi = 0; mi < 4; mi++)
#pragma unroll
    for (int ni = 0; ni < 4; ni++)
#pragma unroll
      for (int vv = 0; vv < 4; ++vv) {
        long row = bm + wm + mi * 16 + quad * 4 + vv;
        long col = bn + wn + ni * 16 + l15;
        Cp[row * N + col] = acc[mi][ni][vv];
      }
}

// ---------------- fused LoRA-mix (xx recomputed inline) ----------------
__global__ __launch_bounds__(256)
void mix_lora(const float* __restrict__ x,
              const float* __restrict__ m5, const float* __restrict__ w2,
              const float* __restrict__ tmw, const float* __restrict__ tmk,
              const float* __restrict__ tmv, const float* __restrict__ tmr,
              const float* __restrict__ tmg,
              unsigned short* __restrict__ xw, unsigned short* __restrict__ xk,
              unsigned short* __restrict__ xv, unsigned short* __restrict__ xr,
              unsigned short* __restrict__ xg) {
  const int bt0 = blockIdx.x * 16;
  const int tid = threadIdx.x;
  const float* tms[5] = {tmw, tmk, tmv, tmr, tmg};
  unsigned short* outs[5] = {xw, xk, xv, xr, xg};
  for (int cc = 0; cc < 8; ++cc) {
    const int c = cc * 256 + tid;
    float xv_[16], xxv_[16];
#pragma unroll
    for (int b = 0; b < 16; b++) {
      const int bt = bt0 + b;
      size_t idx = ((size_t)bt << 11) + c;
      float xc = x[idx];
      float xp = ((bt & 2047) > 0) ? x[idx - 2048] : 0.f;
      xv_[b] = xc; xxv_[b] = xp - xc;
    }
#pragma unroll
    for (int f = 0; f < 5; ++f) {
      const float tmf = tms[f][c];
      float acc[16];
#pragma unroll
      for (int b = 0; b < 16; b++) acc[b] = 0.f;
      for (int dc = 0; dc < 8; ++dc) {
        float wv0 = w2[((size_t)(f * 32 + dc * 4 + 0) << 11) + c];
        float wv1 = w2[((size_t)(f * 32 + dc * 4 + 1) << 11) + c];
        float wv2 = w2[((size_t)(f * 32 + dc * 4 + 2) << 11) + c];
        float wv3 = w2[((size_t)(f * 32 + dc * 4 + 3) << 11) + c];
#pragma unroll
        for (int b = 0; b < 16; b++) {
          float4 mv = *(const float4*)&m5[((size_t)(bt0 + b) << 8) + f * 32 + dc * 4];
          acc[b] += mv.x * wv0 + mv.y * wv1 + mv.z * wv2 + mv.w * wv3;
        }
      }
#pragma unroll
      for (int b = 0; b < 16; b++) {
        size_t idx = ((size_t)(bt0 + b) << 11) + c;
        outs[f][idx] = f2bf(xv_[b] + xxv_[b] * (tmf + acc[b]));
      }
    }
  }
}

// ---------------- decay: dec = exp(-exp(td + t1 @ decay_w2)) (f32) ----------------
__global__ __launch_bounds__(256)
void decay_kernel(const float* __restrict__ t1, const float* __restrict__ w2d,
                  const float* __restrict__ td, float* __restrict__ dec) {
  const int bt0 = blockIdx.x * 16;
  const int tid = threadIdx.x;
  for (int cc = 0; cc < 8; ++cc) {
    const int a = cc * 256 + tid;
    const float tda = td[a];
    float acc[16];
#pragma unroll
    for (int b = 0; b < 16; b++) acc[b] = 0.f;
    for (int dc = 0; dc < 16; ++dc) {
      float wv0 = w2d[((size_t)(dc * 4 + 0) << 11) + a];
      float wv1 = w2d[((size_t)(dc * 4 + 1) << 11) + a];
      float wv2 = w2d[((size_t)(dc * 4 + 2) << 11) + a];
      float wv3 = w2d[((size_t)(dc * 4 + 3) << 11) + a];
#pragma unroll
      for (int b = 0; b < 16; b++) {
        float4 mv = *(const float4*)&t1[((size_t)(bt0 + b) << 7) + dc * 4];
        acc[b] += mv.x * wv0 + mv.y * wv1 + mv.z * wv2 + mv.w * wv3;
      }
    }
#pragma unroll
    for (int b = 0; b < 16; b++) {
      dec[((size_t)(bt0 + b) << 11) + a] = __expf(-__expf(tda + acc[b]));
    }
  }
}

// ---------------- WKV6 chunk-parallel (MFMA) + fused GroupNorm*g, 8 waves ----------------
// block = one (b,h), 512 threads = 8 waves (2/SIMD). Chunk L=64 over T.
// Wave w: wr=w>>1 (C-row quarter), wc=w&1 (C-col half) -> each wave owns a
// 16x32 C region per MFMA phase. Loading/operand-build: wave owns 8 rows
// (rq = w*8). Next-chunk inputs prefetched into the same registers at phase-2
// start (last use is phase 1b). Transposed KT/VT writes batched as
// ds_write_b128 (8 cols per lane-row; 8-aligned so XOR-8 swizzle keeps
// contiguity). GN partials exchanged between wave pairs via LDS.
template<int KF32>
__global__ __launch_bounds__(512, 1)
void wkv6_chunk(const unsigned short* __restrict__ r, const unsigned short* __restrict__ k16,
                const float* __restrict__ k32, const float* __restrict__ v,
                const float* __restrict__ dec, const float* __restrict__ u,
                unsigned short* __restrict__ gz, unsigned short* __restrict__ zlo,
                const float* __restrict__ lnw, const float* __restrict__ lnb) {
  __shared__ unsigned short Rh[4096], Rl[4096];     // R~ [t][i]
  __shared__ unsigned short Kh[4096], Kl[4096];     // K~ [s][i]
  __shared__ unsigned short KTh[4096], KTl[4096];   // K~^T [i][s]
  __shared__ unsigned short VTh[4096], VTl[4096];   // V^T [j][s]
  __shared__ unsigned short Amh[4096], Aml[4096];   // masked A [t][s]
  __shared__ unsigned short SThi[4096], STlo[4096]; // S^T bf16 [j][i]
  __shared__ float STf[4096];                       // S^T f32 [j][i] (persistent)
  __shared__ float qpart[8][64];
  __shared__ float LcEnd[64];
  __shared__ float diagv[64];
  __shared__ float gnp[8][16][2];                   // per-wave GN partials

  const int bh = blockIdx.x, b = bh >> 5, h = bh & 31;
  const int tid = threadIdx.x;
  const int w = tid >> 6, lane = tid & 63;
  const int quad = lane >> 4, l15 = lane & 15;
  const int cb = h * 64;
  const int wr = w >> 1, wc = w & 1;
  const int rq = w * 8;            // operand-build row base (8 rows)
  const int mrow = wr * 16;        // MFMA C row base
  const int mcol = wc * 32;        // MFMA C col base

  const float uu = u[cb + lane];
  float lnwv[2], lnbv[2];
#pragma unroll
  for (int ni = 0; ni < 2; ++ni) {
    lnwv[ni] = lnw[cb + mcol + ni * 16 + l15];
    lnbv[ni] = lnb[cb + mcol + ni * 16 + l15];
  }

  for (int i = tid; i < 4096; i += 512) STf[i] = 0.f;

  const size_t bT = (size_t)b * T_;

  // preload chunk 0 inputs (8 rows x {dec,r,k,v} per lane)
  float dA[8], rA[8], kA[8], vA[8];
  {
    const size_t ro = (bT + rq) * (size_t)A_ + cb + lane;
#pragma unroll
    for (int q = 0; q < 8; ++q) {
      const size_t o = ro + (size_t)q * A_;
      dA[q] = dec[o];
      rA[q] = bf2f(r[o]);
      if (KF32) kA[q] = k32[o];
      else      kA[q] = bf2f(k16[o]);
      vA[q] = v[o];
    }
  }

  for (int c = 0; c < T_ / 64; ++c) {
    const int t0 = c * 64;
    // ---------- phase 1a: local cumprod over this wave's 8 rows ----------
    float lcq[8];
    lcq[0] = dA[0];
#pragma unroll
    for (int q = 1; q < 8; ++q) lcq[q] = lcq[q - 1] * dA[q];
    qpart[w][lane] = lcq[7];
    __syncthreads();                                  // B1 (also orders STf init/update)
    // ---------- phase 1b: build operand tiles ----------
    {
      float pre = 1.f;
#pragma unroll
      for (int pw = 0; pw < 7; ++pw)
        if (pw < w) pre *= qpart[pw][lane];
      if (w == 7) LcEnd[lane] = pre * lcq[7];
      unsigned short hh, ll;
      // S^T bf16 rebuild for rows rq..rq+7
#pragma unroll
      for (int q = 0; q < 8; ++q) {
        const int jr = rq + q;
        split_hl(STf[jr * 64 + lane], hh, ll);
        const int ixs = swz(jr, lane);
        SThi[ixs] = hh; STlo[ixs] = ll;
      }
      // R/K rows + batched KT/VT values + diag
      short8 ktph, ktpl, vtph, vtpl;
#pragma unroll
      for (int q = 0; q < 8; ++q) {
        const int tr = rq + q;
        const float Pl = q ? pre * lcq[q - 1] : pre;
        const float Lc = pre * lcq[q];
        const int ix = swz(tr, lane);
        split_hl(rA[q] * Pl, hh, ll);
        Rh[ix] = hh; Rl[ix] = ll;
        const float kn = kA[q] / Lc;
        split_hl(kn, hh, ll);
        Kh[ix] = hh; Kl[ix] = ll;
        ktph[q] = (short)hh; ktpl[q] = (short)ll;
        split_hl(vA[q], hh, ll);
        vtph[q] = (short)hh; vtpl[q] = (short)ll;
        float dp = rA[q] * uu * kA[q];
        dp += __shfl_xor(dp, 1, 64);
        dp += __shfl_xor(dp, 2, 64);
        dp += __shfl_xor(dp, 4, 64);
        dp += __shfl_xor(dp, 8, 64);
        dp += __shfl_xor(dp, 16, 64);
        dp += __shfl_xor(dp, 32, 64);
        if (lane == 0) diagv[tr] = dp;
      }
      // transposed tiles: row = lane, cols rq..rq+7 (8-aligned, swizzle keeps 16B contiguity)
      const int ixT = lane * 64 + (rq ^ ((lane & 7) << 3));
      *(short8*)&KTh[ixT] = ktph;
      *(short8*)&KTl[ixT] = ktpl;
      *(short8*)&VTh[ixT] = vtph;
      *(short8*)&VTl[ixT] = vtpl;
    }
    __syncthreads();                                  // B2: tiles ready
    // ---------- prefetch next chunk inputs (overwrites dA..vA; last use was 1b) ----------
    if (c + 1 < T_ / 64) {
      const size_t ro = (bT + t0 + 64 + rq) * (size_t)A_ + cb + lane;
#pragma unroll
      for (int q = 0; q < 8; ++q) {
        const size_t o = ro + (size_t)q * A_;
        dA[q] = dec[o];
        rA[q] = bf2f(r[o]);
        if (KF32) kA[q] = k32[o];
        else      kA[q] = bf2f(k16[o]);
        vA[q] = v[o];
      }
    }
    // ---------- phase 2: A = R~ K~^T (16x32 region per wave), mask, store hi/lo ----------
    {
      short8 arh[2], arl[2];
#pragma unroll
      for (int kst = 0; kst < 2; ++kst) {
        const int c8 = kst * 32 + quad * 8;
        arh[kst] = ldfrag(Rh, mrow + l15, c8);
        arl[kst] = ldfrag(Rl, mrow + l15, c8);
      }
      floatx4 acc[2];
#pragma unroll
      for (int ni = 0; ni < 2; ++ni) { floatx4 z = {0.f, 0.f, 0.f, 0.f}; acc[ni] = z; }
#pragma unroll
      for (int ni = 0; ni < 2; ++ni)
#pragma unroll
        for (int kst = 0; kst < 2; ++kst) {
          const int c8 = kst * 32 + quad * 8;
          short8 bh_ = ldfrag(Kh, mcol + ni * 16 + l15, c8);
          short8 bl_ = ldfrag(Kl, mcol + ni * 16 + l15, c8);
          acc[ni] = __builtin_amdgcn_mfma_f32_16x16x32_bf16(arh[kst], bh_, acc[ni], 0, 0, 0);
          acc[ni] = __builtin_amdgcn_mfma_f32_16x16x32_bf16(arh[kst], bl_, acc[ni], 0, 0, 0);
          acc[ni] = __builtin_amdgcn_mfma_f32_16x16x32_bf16(arl[kst], bh_, acc[ni], 0, 0, 0);
        }
#pragma unroll
      for (int ni = 0; ni < 2; ++ni)
#pragma unroll
        for (int vv = 0; vv < 4; ++vv) {
          const int grow = mrow + quad * 4 + vv;
          const int gcol = mcol + ni * 16 + l15;
          float val = (grow > gcol) ? acc[ni][vv] : ((grow == gcol) ? diagv[grow] : 0.f);
          unsigned short hh, ll;
          split_hl(val, hh, ll);
          const int ix = swz(grow, gcol);
          Amh[ix] = hh; Aml[ix] = ll;
        }
    }
    __syncthreads();                                  // B3: Am ready (prefetch drains here)
    // ---------- phase 3: Y = A V + R~ S0, GN*g epilogue ----------
    {
      short8 aAh[2], aAl[2], aRh[2], aRl[2];
#pragma unroll
      for (int kst = 0; kst < 2; ++kst) {
        const int c8 = kst * 32 + quad * 8;
        aAh[kst] = ldfrag(Amh, mrow + l15, c8);
        aAl[kst] = ldfrag(Aml, mrow + l15, c8);
        aRh[kst] = ldfrag(Rh, mrow + l15, c8);
        aRl[kst] = ldfrag(Rl, mrow + l15, c8);
      }
      floatx4 acc[2];
#pragma unroll
      for (int ni = 0; ni < 2; ++ni) { floatx4 z = {0.f, 0.f, 0.f, 0.f}; acc[ni] = z; }
#pragma unroll
      for (int ni = 0; ni < 2; ++ni)
#pragma unroll
        for (int kst = 0; kst < 2; ++kst) {
          const int c8 = kst * 32 + quad * 8;
          const int brow = mcol + ni * 16 + l15;
          short8 bvh = ldfrag(VTh, brow, c8);
          short8 bvl = ldfrag(VTl, brow, c8);
          acc[ni] = __builtin_amdgcn_mfma_f32_16x16x32_bf16(aAh[kst], bvh, acc[ni], 0, 0, 0);
          acc[ni] = __builtin_amdgcn_mfma_f32_16x16x32_bf16(aAh[kst], bvl, acc[ni], 0, 0, 0);
          acc[ni] = __builtin_amdgcn_mfma_f32_16x16x32_bf16(aAl[kst], bvh, acc[ni], 0, 0, 0);
          short8 bsh = ldfrag(SThi, brow, c8);
          short8 bsl = ldfrag(STlo, brow, c8);
          acc[ni] = __builtin_amdgcn_mfma_f32_16x16x32_bf16(aRh[kst], bsh, acc[ni], 0, 0, 0);
          acc[ni] = __builtin_amdgcn_mfma_f32_16x16x32_bf16(aRh[kst], bsl, acc[ni], 0, 0, 0);
          acc[ni] = __builtin_amdgcn_mfma_f32_16x16x32_bf16(aRl[kst], bsh, acc[ni], 0, 0, 0);
        }
      // GN partials over this wave's 32 cols; exchange with partner wave (w^1)
      float s1_[4], s2_[4];
#pragma unroll
      for (int vv = 0; vv < 4; ++vv) {
        float s1 = acc[0][vv] + acc[1][vv];
        float s2 = acc[0][vv] * acc[0][vv] + acc[1][vv] * acc[1][vv];
        s1 += __shfl_xor(s1, 1, 64); s2 += __shfl_xor(s2, 1, 64);
        s1 += __shfl_xor(s1, 2, 64); s2 += __shfl_xor(s2, 2, 64);
        s1 += __shfl_xor(s1, 4, 64); s2 += __shfl_xor(s2, 4, 64);
        s1 += __shfl_xor(s1, 8, 64); s2 += __shfl_xor(s2, 8, 64);
        s1_[vv] = s1; s2_[vv] = s2;
        if (l15 == 0) {
          gnp[w][quad * 4 + vv][0] = s1;
          gnp[w][quad * 4 + vv][1] = s2;
        }
      }
      __syncthreads();                                // B4: GN partials ready
#pragma unroll
      for (int ni = 0; ni < 2; ++ni)
#pragma unroll
        for (int vv = 0; vv < 4; ++vv) {
          const int rloc = quad * 4 + vv;
          float s1 = s1_[vv] + gnp[w ^ 1][rloc][0];
          float s2 = s2_[vv] + gnp[w ^ 1][rloc][1];
          float mu = s1 * (1.f / 64.f);
          float var = s2 * (1.f / 64.f) - mu * mu;
          float rs = rsqrtf(var + 6.4e-4f);           // EPS = 1e-5 * 64
          const size_t off = (bT + t0 + mrow + rloc) * (size_t)A_ + cb + mcol + ni * 16 + l15;
          float yn = (acc[ni][vv] - mu) * rs * lnwv[ni] + lnbv[ni];
          float z = yn * bf2f(gz[off]);
          unsigned short zh = f2bf(z);
          gz[off] = zh;
          zlo[off] = f2bf(z - bf2f(zh));
        }
    }
    // ---------- phase 4: S^T = LcEnd .*cols ( V^T K~ + S^T ) ----------
    {
      short8 avh[2], avl[2];
#pragma unroll
      for (int kst = 0; kst < 2; ++kst) {
        const int c8 = kst * 32 + quad * 8;
        avh[kst] = ldfrag(VTh, mrow + l15, c8);
        avl[kst] = ldfrag(VTl, mrow + l15, c8);
      }
      floatx4 a4[2];
#pragma unroll
      for (int ni = 0; ni < 2; ++ni) { floatx4 z = {0.f, 0.f, 0.f, 0.f}; a4[ni] = z; }
#pragma unroll
      for (int ni = 0; ni < 2; ++ni)
#pragma unroll
        for (int kst = 0; kst < 2; ++kst) {
          const int c8 = kst * 32 + quad * 8;
          short8 bkh = ldfrag(KTh, mcol + ni * 16 + l15, c8);
          short8 bkl = ldfrag(KTl, mcol + ni * 16 + l15, c8);
          a4[ni] = __builtin_amdgcn_mfma_f32_16x16x32_bf16(avh[kst], bkh, a4[ni], 0, 0, 0);
          a4[ni] = __builtin_amdgcn_mfma_f32_16x16x32_bf16(avh[kst], bkl, a4[ni], 0, 0, 0);
          a4[ni] = __builtin_amdgcn_mfma_f32_16x16x32_bf16(avl[kst], bkh, a4[ni], 0, 0, 0);
        }
#pragma unroll
      for (int ni = 0; ni < 2; ++ni) {
        const float lce = LcEnd[mcol + ni * 16 + l15];
#pragma unroll
        for (int vv = 0; vv < 4; ++vv) {
          const int jr = mrow + quad * 4 + vv;
          const int ic = mcol + ni * 16 + l15;
          STf[jr * 64 + ic] = lce * (a4[ni][vv] + STf[jr * 64 + ic]);
        }
      }
    }
    __syncthreads();                                  // B5: tiles/STf stable for next chunk
  }
}

// ---------------- launch ----------------
extern "C" void kernel_launch(void* const* d_in, const int* in_sizes, int n_in,
                              void* d_out, int out_size, void* d_ws, size_t ws_size,
                              hipStream_t stream) {
  (void)in_sizes; (void)n_in; (void)out_size;
  const float* x   = (const float*)d_in[0];
  const float* tmx = (const float*)d_in[1];
  const float* tmw = (const float*)d_in[2];
  const float* tmk = (const float*)d_in[3];
  const float* tmv = (const float*)d_in[4];
  const float* tmr = (const float*)d_in[5];
  const float* tmg = (const float*)d_in[6];
  const float* w1  = (const float*)d_in[7];   // (C,160)
  const float* w2  = (const float*)d_in[8];   // (5,32,C)
  const float* td  = (const float*)d_in[9];   // (A)
  const float* dw1 = (const float*)d_in[10];  // (C,64)
  const float* dw2 = (const float*)d_in[11];  // (64,A)
  const float* u   = (const float*)d_in[12];  // (H,N)
  const float* Wr  = (const float*)d_in[13];
  const float* Wk  = (const float*)d_in[14];
  const float* Wv  = (const float*)d_in[15];
  const float* Wg  = (const float*)d_in[16];
  const float* Wo  = (const float*)d_in[17];
  const float* lnw = (const float*)d_in[18];
  const float* lnb = (const float*)d_in[19];

  char* ws = (char*)d_ws;
  const size_t MB = 1024 * 1024;
  // 472MB layout (proven safe footprint), lifetime-overlapped:
  // [0,64)    U0: xxx -> g -> z_hi (in place)
  // [64,80)       m5 (f32, 16MB) -> later v-f32 lower half spans [64,128)
  // [128,192) U2: bxk (w1T scratch at [128,129) pre-mix) -> v-f32 upper half
  // [192,256) U3: bxv -> dec lower half
  // [256,320) U4: bxw -> dec upper half     (dec = [192,320) f32, read-only in chunk kernel)
  // [320,384) U5: bxg -> r -> z_lo overlay (chunk kernel)
  // [384,448) U6: bxr -> k (bf16, L0)
  // [448,464)     W_hi/W_lo scratch (dw1T pre) -> W_hi/W_lo (Wo)
  // [464,472)     t1 (f32, 8MB)
  unsigned short* xxx  = (unsigned short*)(ws + 0 * MB);
  unsigned short* gb   = (unsigned short*)(ws + 0 * MB);     // z_hi
  float*          m5   = (float*)(ws + 64 * MB);
  float*          vf   = (float*)(ws + 64 * MB);             // v f32 [64,192)
  unsigned short* w1T  = (unsigned short*)(ws + 128 * MB);
  unsigned short* bxk  = (unsigned short*)(ws + 128 * MB);
  unsigned short* bxv  = (unsigned short*)(ws + 192 * MB);
  float*          decb = (float*)(ws + 192 * MB);            // dec f32 [192,320)
  unsigned short* bxw  = (unsigned short*)(ws + 256 * MB);
  unsigned short* bxg  = (unsigned short*)(ws + 320 * MB);
  unsigned short* rb   = (unsigned short*)(ws + 320 * MB);   // r, then z_lo overlay
  unsigned short* bxr  = (unsigned short*)(ws + 384 * MB);
  unsigned short* kb   = (unsigned short*)(ws + 384 * MB);   // k bf16 (L0)
  unsigned short* dw1T = (unsigned short*)(ws + 448 * MB);
  unsigned short* Whi  = (unsigned short*)(ws + 448 * MB);
  unsigned short* Wlo  = (unsigned short*)(ws + 456 * MB);
  float*          t1   = (float*)(ws + 464 * MB);
  // optional upgrade: k in f32 at [480,608) if workspace allows (runtime-constant branch)
  const bool kf32 = ws_size >= (size_t)616 * MB;
  float* kf = (float*)(ws + 480 * MB);

  const int nW = A_ * C_;  // 4.19M elements
  const size_t EBT = (size_t)BT_ * C_;

  // 1. token-shift mix -> xxx
  shift_mix<<<(int)(EBT / 4 / 256), 256, 0, stream>>>(x, tmx, xxx);

  // 2. m5 = tanh(xxx @ maa_w1) padded N=256
  transpose_pad<<<(256 * 2048) / 256, 256, 0, stream>>>(w1, w1T, 256, 160);
  gemm_bt<2><<<dim3(BT_ / 128, 2), 256, 0, stream>>>(xxx, w1T, m5, BT_, 256, 2048);

  // 3. five mixed inputs
  mix_lora<<<BT_ / 16, 256, 0, stream>>>(x, m5, w2, tmw, tmk, tmv, tmr, tmg,
                                         bxw, bxk, bxv, bxr, bxg);

  // 4. t1 = tanh(xw @ decay_w1) padded N=128
  transpose_pad<<<(128 * 2048) / 256, 256, 0, stream>>>(dw1, dw1T, 128, 64);
  gemm_bt<2><<<dim3(BT_ / 128, 1), 256, 0, stream>>>(bxw, dw1T, t1, BT_, 128, 2048);

  // 5-8. projections with split-exact weights (order matters for slot recycling)
  conv_hilo<<<nW / 256, 256, 0, stream>>>(Wg, Whi, Wlo, nW);
  gemm_sb<1><<<dim3(BT_ / 128, 16), 256, 0, stream>>>(bxg, Whi, Wlo, gb, BT_, 2048, 2048);
  conv_hilo<<<nW / 256, 256, 0, stream>>>(Wr, Whi, Wlo, nW);
  gemm_sb<0><<<dim3(BT_ / 128, 16), 256, 0, stream>>>(bxr, Whi, Wlo, rb, BT_, 2048, 2048);
  conv_hilo<<<nW / 256, 256, 0, stream>>>(Wk, Whi, Wlo, nW);
  if (kf32) {
    gemm_sb<3><<<dim3(BT_ / 128, 16), 256, 0, stream>>>(bxk, Whi, Wlo, kf, BT_, 2048, 2048);
  } else {
    gemm_sb<0><<<dim3(BT_ / 128, 16), 256, 0, stream>>>(bxk, Whi, Wlo, kb, BT_, 2048, 2048);
  }
  conv_hilo<<<nW / 256, 256, 0, stream>>>(Wv, Whi, Wlo, nW);
  gemm_sb<3><<<dim3(BT_ / 128, 16), 256, 0, stream>>>(bxv, Whi, Wlo, vf, BT_, 2048, 2048);

  // 9. dec (after bxv/bxw are dead; overlays them)
  decay_kernel<<<BT_ / 16, 256, 0, stream>>>(t1, dw2, td, decb);

  // 10. WKV6 chunk-parallel MFMA (8 waves) + fused GroupNorm*g -> z_hi (over g), z_lo (over r)
  if (kf32) {
    wkv6_chunk<1><<<256, 512, 0, stream>>>(rb, kb, kf, vf, decb, u, gb, rb, lnw, lnb);
  } else {
    wkv6_chunk<0><<<256, 512, 0, stream>>>(rb, kb, kf, vf, decb, u, gb, rb, lnw, lnb);
  }

  // 11. output projection: (z_hi + z_lo) @ (Wo_hi + Wo_lo)^T -> d_out (f32)
  conv_hilo<<<nW / 256, 256, 0, stream>>>(Wo, Whi, Wlo, nW);
  gemm_s3<<<dim3(BT_ / 128, 16), 256, 0, stream>>>(gb, rb, Whi, Wlo, (float*)d_out, BT_, 2048, 2048);
}

// Round 6
// 2147.935 us; speedup vs baseline: 1.6098x; 1.3190x over previous
//
#include <hip/hip_runtime.h>
#include <hip/hip_bf16.h>
#include <cstdint>
#include <cstddef>

#define B_ 8
#define T_ 2048
#define C_ 2048
#define A_ 2048
#define H_ 32
#define BT_ (B_*T_)

typedef short short8 __attribute__((ext_vector_type(8)));
typedef _Float16 half8 __attribute__((ext_vector_type(8)));
typedef float floatx4 __attribute__((ext_vector_type(4)));

__device__ __forceinline__ unsigned short f2bf(float f) {
  union { float f; uint32_t u; } a; a.f = f;
  uint32_t r = a.u + 0x7fffu + ((a.u >> 16) & 1u);   // RNE
  return (unsigned short)(r >> 16);
}
__device__ __forceinline__ float bf2f(unsigned short s) {
  union { uint32_t u; float f; } a; a.u = ((uint32_t)s) << 16;
  return a.f;
}
__device__ __forceinline__ unsigned short f2h(float f) {
  union { _Float16 h; unsigned short u; } c; c.h = (_Float16)f; return c.u;
}
__device__ __forceinline__ float h2f(unsigned short u) {
  union { unsigned short u; _Float16 h; } c; c.u = u; return (float)c.h;
}
__device__ __forceinline__ void split_hl(float v, unsigned short& hh, unsigned short& ll) {
  hh = f2bf(v);
  ll = f2bf(v - bf2f(hh));
}
// XOR-swizzled index into a row-major [64][64] bf16 LDS tile (G4 recipe)
__device__ __forceinline__ int swz(int row, int col) {
  return row * 64 + (col ^ ((row & 7) << 3));
}
__device__ __forceinline__ short8 ldfrag(const unsigned short* M, int row, int col8) {
  return *(const short8*)&M[row * 64 + (col8 ^ ((row & 7) << 3))];
}

// ---------------- weight prep: f32 -> f16 ----------------
__global__ void conv_f16(const float* __restrict__ s, unsigned short* __restrict__ d, int n) {
  int i = blockIdx.x * 256 + threadIdx.x;
  if (i < n) d[i] = f2h(s[i]);
}

// src (2048 x NV) f32 -> dst (NP x 2048) f16, rows >= NV zero-padded
__global__ void transpose_pad(const float* __restrict__ s, unsigned short* __restrict__ d, int NP, int NV) {
  int i = blockIdx.x * 256 + threadIdx.x;  // over NP*2048
  int n = i >> 11, kk = i & 2047;
  if (n < NP) d[i] = (n < NV) ? f2h(s[kk * NV + n]) : (unsigned short)0;
}

// ---------------- token shift + maa_x mix (f16 out) ----------------
__global__ void shift_mix(const float* __restrict__ x, const float* __restrict__ tmx,
                          unsigned short* __restrict__ xxx) {
  size_t i4 = (size_t)blockIdx.x * 256 + threadIdx.x;   // over BT*C/4
  size_t i = i4 * 4;
  int c = (int)(i & 2047);
  int t = (int)((i >> 11) & 2047);
  float4 xv = *(const float4*)&x[i];
  float4 pv = make_float4(0.f, 0.f, 0.f, 0.f);
  if (t > 0) pv = *(const float4*)&x[i - 2048];
  float4 tv = *(const float4*)&tmx[c];
  ushort4 m;
  m.x = f2h(xv.x + (pv.x - xv.x) * tv.x);
  m.y = f2h(xv.y + (pv.y - xv.y) * tv.y);
  m.z = f2h(xv.z + (pv.z - xv.z) * tv.z);
  m.w = f2h(xv.w + (pv.w - xv.w) * tv.w);
  *(ushort4*)&xxx[i] = m;
}

// ---------------- async global->LDS helper ----------------
__device__ __forceinline__ void gll16(const void* g, void* l) {
  __builtin_amdgcn_global_load_lds(
      (const __attribute__((address_space(1))) void*)g,
      (__attribute__((address_space(3))) void*)l, 16, 0, 0);
}

// ---------------- f16 GEMM: C = A * B^T ----------------
// EPI: 0 = ->bf16, 1 = silu->f16, 2 = tanh->f32, 3 = ->f32
template<int EPI>
__global__ __launch_bounds__(256)
void gemm_f16(const unsigned short* __restrict__ Am, const unsigned short* __restrict__ Bm,
              void* __restrict__ Cp, int M, int N, int K) {
  __shared__ unsigned short As[128 * 32];
  __shared__ unsigned short Bs[128 * 32];
  const int tid = threadIdx.x;
  const int wid = tid >> 6, lane = tid & 63;
  const int quad = lane >> 4, l15 = lane & 15;
  const long bm = (long)blockIdx.x * 128, bn = (long)blockIdx.y * 128;
  const int wm = (wid & 1) * 64, wn = (wid >> 1) * 64;

  floatx4 acc[4][4];
#pragma unroll
  for (int a = 0; a < 4; a++)
#pragma unroll
    for (int b = 0; b < 4; b++) { floatx4 z = {0.f, 0.f, 0.f, 0.f}; acc[a][b] = z; }

  const int stg_row = wid * 32 + (lane >> 2);
  const int stg_k   = (lane & 3) * 8;
  const int stg_lds = wid * 1024 + lane * 8;

  for (int k0 = 0; k0 < K; k0 += 32) {
    __syncthreads();
#pragma unroll
    for (int p = 0; p < 2; ++p) {
      gll16(Am + (bm + stg_row + p * 16) * (long)K + k0 + stg_k, &As[stg_lds + p * 512]);
      gll16(Bm + (bn + stg_row + p * 16) * (long)K + k0 + stg_k, &Bs[stg_lds + p * 512]);
    }
    __syncthreads();

    half8 af[4], bfr[4];
#pragma unroll
    for (int mi = 0; mi < 4; mi++) af[mi] = *(const half8*)&As[(wm + mi * 16 + l15) * 32 + quad * 8];
#pragma unroll
    for (int ni = 0; ni < 4; ni++) bfr[ni] = *(const half8*)&Bs[(wn + ni * 16 + l15) * 32 + quad * 8];
#pragma unroll
    for (int mi = 0; mi < 4; mi++)
#pragma unroll
      for (int ni = 0; ni < 4; ni++)
        acc[mi][ni] = __builtin_amdgcn_mfma_f32_16x16x32_f16(af[mi], bfr[ni], acc[mi][ni], 0, 0, 0);
  }

#pragma unroll
  for (int mi = 0; mi < 4; mi++)
#pragma unroll
    for (int ni = 0; ni < 4; ni++)
#pragma unroll
      for (int vv = 0; vv < 4; ++vv) {
        long row = bm + wm + mi * 16 + quad * 4 + vv;
        long col = bn + wn + ni * 16 + l15;
        float val = acc[mi][ni][vv];
        if (EPI == 0) {
          ((unsigned short*)Cp)[row * N + col] = f2bf(val);
        } else if (EPI == 1) {
          float s = val / (1.f + __expf(-val));
          ((unsigned short*)Cp)[row * N + col] = f2h(s);
        } else if (EPI == 2) {
          ((float*)Cp)[row * N + col] = tanhf(val);
        } else {
          ((float*)Cp)[row * N + col] = val;
        }
      }
}

// ---------------- fused LoRA-mix (xx recomputed inline, f16 out) ----------------
__global__ __launch_bounds__(256)
void mix_lora(const float* __restrict__ x,
              const float* __restrict__ m5, const float* __restrict__ w2,
              const float* __restrict__ tmw, const float* __restrict__ tmk,
              const float* __restrict__ tmv, const float* __restrict__ tmr,
              const float* __restrict__ tmg,
              unsigned short* __restrict__ xw, unsigned short* __restrict__ xk,
              unsigned short* __restrict__ xv, unsigned short* __restrict__ xr,
              unsigned short* __restrict__ xg) {
  const int bt0 = blockIdx.x * 16;
  const int tid = threadIdx.x;
  const float* tms[5] = {tmw, tmk, tmv, tmr, tmg};
  unsigned short* outs[5] = {xw, xk, xv, xr, xg};
  for (int cc = 0; cc < 8; ++cc) {
    const int c = cc * 256 + tid;
    float xv_[16], xxv_[16];
#pragma unroll
    for (int b = 0; b < 16; b++) {
      const int bt = bt0 + b;
      size_t idx = ((size_t)bt << 11) + c;
      float xc = x[idx];
      float xp = ((bt & 2047) > 0) ? x[idx - 2048] : 0.f;
      xv_[b] = xc; xxv_[b] = xp - xc;
    }
#pragma unroll
    for (int f = 0; f < 5; ++f) {
      const float tmf = tms[f][c];
      float acc[16];
#pragma unroll
      for (int b = 0; b < 16; b++) acc[b] = 0.f;
      for (int dc = 0; dc < 8; ++dc) {
        float wv0 = w2[((size_t)(f * 32 + dc * 4 + 0) << 11) + c];
        float wv1 = w2[((size_t)(f * 32 + dc * 4 + 1) << 11) + c];
        float wv2 = w2[((size_t)(f * 32 + dc * 4 + 2) << 11) + c];
        float wv3 = w2[((size_t)(f * 32 + dc * 4 + 3) << 11) + c];
#pragma unroll
        for (int b = 0; b < 16; b++) {
          float4 mv = *(const float4*)&m5[((size_t)(bt0 + b) << 8) + f * 32 + dc * 4];
          acc[b] += mv.x * wv0 + mv.y * wv1 + mv.z * wv2 + mv.w * wv3;
        }
      }
#pragma unroll
      for (int b = 0; b < 16; b++) {
        size_t idx = ((size_t)(bt0 + b) << 11) + c;
        outs[f][idx] = f2h(xv_[b] + xxv_[b] * (tmf + acc[b]));
      }
    }
  }
}

// ---------------- decay: dec = exp(-exp(td + t1 @ decay_w2)) (f32) ----------------
__global__ __launch_bounds__(256)
void decay_kernel(const float* __restrict__ t1, const float* __restrict__ w2d,
                  const float* __restrict__ td, float* __restrict__ dec) {
  const int bt0 = blockIdx.x * 16;
  const int tid = threadIdx.x;
  for (int cc = 0; cc < 8; ++cc) {
    const int a = cc * 256 + tid;
    const float tda = td[a];
    float acc[16];
#pragma unroll
    for (int b = 0; b < 16; b++) acc[b] = 0.f;
    for (int dc = 0; dc < 16; ++dc) {
      float wv0 = w2d[((size_t)(dc * 4 + 0) << 11) + a];
      float wv1 = w2d[((size_t)(dc * 4 + 1) << 11) + a];
      float wv2 = w2d[((size_t)(dc * 4 + 2) << 11) + a];
      float wv3 = w2d[((size_t)(dc * 4 + 3) << 11) + a];
#pragma unroll
      for (int b = 0; b < 16; b++) {
        float4 mv = *(const float4*)&t1[((size_t)(bt0 + b) << 7) + dc * 4];
        acc[b] += mv.x * wv0 + mv.y * wv1 + mv.z * wv2 + mv.w * wv3;
      }
    }
#pragma unroll
    for (int b = 0; b < 16; b++) {
      dec[((size_t)(bt0 + b) << 11) + a] = __expf(-__expf(tda + acc[b]));
    }
  }
}

// ---------------- WKV6 chunk-parallel (MFMA) + fused GroupNorm*g, 8 waves ----------------
// block = one (b,h), 512 threads = 8 waves (2/SIMD). Chunk L=64 over T.
// Internals stay bf16 hi/lo (K~ = k/Lc can reach ~1e31 -> NOT f16-range-safe).
// g read as f16; z written as f16 in place over g (single buffer, no lo overlay).
template<int KF32>
__global__ __launch_bounds__(512, 1)
void wkv6_chunk(const unsigned short* __restrict__ r, const unsigned short* __restrict__ k16,
                const float* __restrict__ k32, const float* __restrict__ v,
                const float* __restrict__ dec, const float* __restrict__ u,
                unsigned short* __restrict__ gz,
                const float* __restrict__ lnw, const float* __restrict__ lnb) {
  __shared__ unsigned short Rh[4096], Rl[4096];     // R~ [t][i]
  __shared__ unsigned short Kh[4096], Kl[4096];     // K~ [s][i]
  __shared__ unsigned short KTh[4096], KTl[4096];   // K~^T [i][s]
  __shared__ unsigned short VTh[4096], VTl[4096];   // V^T [j][s]
  __shared__ unsigned short Amh[4096], Aml[4096];   // masked A [t][s]
  __shared__ unsigned short SThi[4096], STlo[4096]; // S^T bf16 [j][i]
  __shared__ float STf[4096];                       // S^T f32 [j][i] (persistent)
  __shared__ float qpart[8][64];
  __shared__ float LcEnd[64];
  __shared__ float diagv[64];
  __shared__ float gnp[8][16][2];                   // per-wave GN partials

  const int bh = blockIdx.x, b = bh >> 5, h = bh & 31;
  const int tid = threadIdx.x;
  const int w = tid >> 6, lane = tid & 63;
  const int quad = lane >> 4, l15 = lane & 15;
  const int cb = h * 64;
  const int wr = w >> 1, wc = w & 1;
  const int rq = w * 8;            // operand-build row base (8 rows)
  const int mrow = wr * 16;        // MFMA C row base
  const int mcol = wc * 32;        // MFMA C col base

  const float uu = u[cb + lane];
  float lnwv[2], lnbv[2];
#pragma unroll
  for (int ni = 0; ni < 2; ++ni) {
    lnwv[ni] = lnw[cb + mcol + ni * 16 + l15];
    lnbv[ni] = lnb[cb + mcol + ni * 16 + l15];
  }

  for (int i = tid; i < 4096; i += 512) STf[i] = 0.f;

  const size_t bT = (size_t)b * T_;

  // preload chunk 0 inputs (8 rows x {dec,r,k,v} per lane)
  float dA[8], rA[8], kA[8], vA[8];
  {
    const size_t ro = (bT + rq) * (size_t)A_ + cb + lane;
#pragma unroll
    for (int q = 0; q < 8; ++q) {
      const size_t o = ro + (size_t)q * A_;
      dA[q] = dec[o];
      rA[q] = bf2f(r[o]);
      if (KF32) kA[q] = k32[o];
      else      kA[q] = bf2f(k16[o]);
      vA[q] = v[o];
    }
  }

  for (int c = 0; c < T_ / 64; ++c) {
    const int t0 = c * 64;
    // ---------- phase 1a: local cumprod over this wave's 8 rows ----------
    float lcq[8];
    lcq[0] = dA[0];
#pragma unroll
    for (int q = 1; q < 8; ++q) lcq[q] = lcq[q - 1] * dA[q];
    qpart[w][lane] = lcq[7];
    __syncthreads();                                  // B1 (also orders STf init/update)
    // ---------- phase 1b: build operand tiles ----------
    {
      float pre = 1.f;
#pragma unroll
      for (int pw = 0; pw < 7; ++pw)
        if (pw < w) pre *= qpart[pw][lane];
      if (w == 7) LcEnd[lane] = pre * lcq[7];
      unsigned short hh, ll;
      // S^T bf16 rebuild for rows rq..rq+7
#pragma unroll
      for (int q = 0; q < 8; ++q) {
        const int jr = rq + q;
        split_hl(STf[jr * 64 + lane], hh, ll);
        const int ixs = swz(jr, lane);
        SThi[ixs] = hh; STlo[ixs] = ll;
      }
      // R/K rows + batched KT/VT values + diag
      short8 ktph, ktpl, vtph, vtpl;
#pragma unroll
      for (int q = 0; q < 8; ++q) {
        const int tr = rq + q;
        const float Pl = q ? pre * lcq[q - 1] : pre;
        const float Lc = pre * lcq[q];
        const int ix = swz(tr, lane);
        split_hl(rA[q] * Pl, hh, ll);
        Rh[ix] = hh; Rl[ix] = ll;
        const float kn = kA[q] / Lc;
        split_hl(kn, hh, ll);
        Kh[ix] = hh; Kl[ix] = ll;
        ktph[q] = (short)hh; ktpl[q] = (short)ll;
        split_hl(vA[q], hh, ll);
        vtph[q] = (short)hh; vtpl[q] = (short)ll;
        float dp = rA[q] * uu * kA[q];
        dp += __shfl_xor(dp, 1, 64);
        dp += __shfl_xor(dp, 2, 64);
        dp += __shfl_xor(dp, 4, 64);
        dp += __shfl_xor(dp, 8, 64);
        dp += __shfl_xor(dp, 16, 64);
        dp += __shfl_xor(dp, 32, 64);
        if (lane == 0) diagv[tr] = dp;
      }
      // transposed tiles: row = lane, cols rq..rq+7 (8-aligned, swizzle keeps 16B contiguity)
      const int ixT = lane * 64 + (rq ^ ((lane & 7) << 3));
      *(short8*)&KTh[ixT] = ktph;
      *(short8*)&KTl[ixT] = ktpl;
      *(short8*)&VTh[ixT] = vtph;
      *(short8*)&VTl[ixT] = vtpl;
    }
    __syncthreads();                                  // B2: tiles ready
    // ---------- prefetch next chunk inputs (overwrites dA..vA; last use was 1b) ----------
    if (c + 1 < T_ / 64) {
      const size_t ro = (bT + t0 + 64 + rq) * (size_t)A_ + cb + lane;
#pragma unroll
      for (int q = 0; q < 8; ++q) {
        const size_t o = ro + (size_t)q * A_;
        dA[q] = dec[o];
        rA[q] = bf2f(r[o]);
        if (KF32) kA[q] = k32[o];
        else      kA[q] = bf2f(k16[o]);
        vA[q] = v[o];
      }
    }
    // ---------- phase 2: A = R~ K~^T (16x32 region per wave), mask, store hi/lo ----------
    {
      short8 arh[2], arl[2];
#pragma unroll
      for (int kst = 0; kst < 2; ++kst) {
        const int c8 = kst * 32 + quad * 8;
        arh[kst] = ldfrag(Rh, mrow + l15, c8);
        arl[kst] = ldfrag(Rl, mrow + l15, c8);
      }
      floatx4 acc[2];
#pragma unroll
      for (int ni = 0; ni < 2; ++ni) { floatx4 z = {0.f, 0.f, 0.f, 0.f}; acc[ni] = z; }
#pragma unroll
      for (int ni = 0; ni < 2; ++ni)
#pragma unroll
        for (int kst = 0; kst < 2; ++kst) {
          const int c8 = kst * 32 + quad * 8;
          short8 bh_ = ldfrag(Kh, mcol + ni * 16 + l15, c8);
          short8 bl_ = ldfrag(Kl, mcol + ni * 16 + l15, c8);
          acc[ni] = __builtin_amdgcn_mfma_f32_16x16x32_bf16(arh[kst], bh_, acc[ni], 0, 0, 0);
          acc[ni] = __builtin_amdgcn_mfma_f32_16x16x32_bf16(arh[kst], bl_, acc[ni], 0, 0, 0);
          acc[ni] = __builtin_amdgcn_mfma_f32_16x16x32_bf16(arl[kst], bh_, acc[ni], 0, 0, 0);
        }
#pragma unroll
      for (int ni = 0; ni < 2; ++ni)
#pragma unroll
        for (int vv = 0; vv < 4; ++vv) {
          const int grow = mrow + quad * 4 + vv;
          const int gcol = mcol + ni * 16 + l15;
          float val = (grow > gcol) ? acc[ni][vv] : ((grow == gcol) ? diagv[grow] : 0.f);
          unsigned short hh, ll;
          split_hl(val, hh, ll);
          const int ix = swz(grow, gcol);
          Amh[ix] = hh; Aml[ix] = ll;
        }
    }
    __syncthreads();                                  // B3: Am ready (prefetch drains here)
    // ---------- phase 3: Y = A V + R~ S0, GN*g epilogue ----------
    {
      short8 aAh[2], aAl[2], aRh[2], aRl[2];
#pragma unroll
      for (int kst = 0; kst < 2; ++kst) {
        const int c8 = kst * 32 + quad * 8;
        aAh[kst] = ldfrag(Amh, mrow + l15, c8);
        aAl[kst] = ldfrag(Aml, mrow + l15, c8);
        aRh[kst] = ldfrag(Rh, mrow + l15, c8);
        aRl[kst] = ldfrag(Rl, mrow + l15, c8);
      }
      floatx4 acc[2];
#pragma unroll
      for (int ni = 0; ni < 2; ++ni) { floatx4 z = {0.f, 0.f, 0.f, 0.f}; acc[ni] = z; }
#pragma unroll
      for (int ni = 0; ni < 2; ++ni)
#pragma unroll
        for (int kst = 0; kst < 2; ++kst) {
          const int c8 = kst * 32 + quad * 8;
          const int brow = mcol + ni * 16 + l15;
          short8 bvh = ldfrag(VTh, brow, c8);
          short8 bvl = ldfrag(VTl, brow, c8);
          acc[ni] = __builtin_amdgcn_mfma_f32_16x16x32_bf16(aAh[kst], bvh, acc[ni], 0, 0, 0);
          acc[ni] = __builtin_amdgcn_mfma_f32_16x16x32_bf16(aAh[kst], bvl, acc[ni], 0, 0, 0);
          acc[ni] = __builtin_amdgcn_mfma_f32_16x16x32_bf16(aAl[kst], bvh, acc[ni], 0, 0, 0);
          short8 bsh = ldfrag(SThi, brow, c8);
          short8 bsl = ldfrag(STlo, brow, c8);
          acc[ni] = __builtin_amdgcn_mfma_f32_16x16x32_bf16(aRh[kst], bsh, acc[ni], 0, 0, 0);
          acc[ni] = __builtin_amdgcn_mfma_f32_16x16x32_bf16(aRh[kst], bsl, acc[ni], 0, 0, 0);
          acc[ni] = __builtin_amdgcn_mfma_f32_16x16x32_bf16(aRl[kst], bsh, acc[ni], 0, 0, 0);
        }
      // GN partials over this wave's 32 cols; exchange with partner wave (w^1)
      float s1_[4], s2_[4];
#pragma unroll
      for (int vv = 0; vv < 4; ++vv) {
        float s1 = acc[0][vv] + acc[1][vv];
        float s2 = acc[0][vv] * acc[0][vv] + acc[1][vv] * acc[1][vv];
        s1 += __shfl_xor(s1, 1, 64); s2 += __shfl_xor(s2, 1, 64);
        s1 += __shfl_xor(s1, 2, 64); s2 += __shfl_xor(s2, 2, 64);
        s1 += __shfl_xor(s1, 4, 64); s2 += __shfl_xor(s2, 4, 64);
        s1 += __shfl_xor(s1, 8, 64); s2 += __shfl_xor(s2, 8, 64);
        s1_[vv] = s1; s2_[vv] = s2;
        if (l15 == 0) {
          gnp[w][quad * 4 + vv][0] = s1;
          gnp[w][quad * 4 + vv][1] = s2;
        }
      }
      __syncthreads();                                // B4: GN partials ready
#pragma unroll
      for (int ni = 0; ni < 2; ++ni)
#pragma unroll
        for (int vv = 0; vv < 4; ++vv) {
          const int rloc = quad * 4 + vv;
          float s1 = s1_[vv] + gnp[w ^ 1][rloc][0];
          float s2 = s2_[vv] + gnp[w ^ 1][rloc][1];
          float mu = s1 * (1.f / 64.f);
          float var = s2 * (1.f / 64.f) - mu * mu;
          float rs = rsqrtf(var + 6.4e-4f);           // EPS = 1e-5 * 64
          const size_t off = (bT + t0 + mrow + rloc) * (size_t)A_ + cb + mcol + ni * 16 + l15;
          float yn = (acc[ni][vv] - mu) * rs * lnwv[ni] + lnbv[ni];
          float z = yn * h2f(gz[off]);
          gz[off] = f2h(z);
        }
    }
    // ---------- phase 4: S^T = LcEnd .*cols ( V^T K~ + S^T ) ----------
    {
      short8 avh[2], avl[2];
#pragma unroll
      for (int kst = 0; kst < 2; ++kst) {
        const int c8 = kst * 32 + quad * 8;
        avh[kst] = ldfrag(VTh, mrow + l15, c8);
        avl[kst] = ldfrag(VTl, mrow + l15, c8);
      }
      floatx4 a4[2];
#pragma unroll
      for (int ni = 0; ni < 2; ++ni) { floatx4 z = {0.f, 0.f, 0.f, 0.f}; a4[ni] = z; }
#pragma unroll
      for (int ni = 0; ni < 2; ++ni)
#pragma unroll
        for (int kst = 0; kst < 2; ++kst) {
          const int c8 = kst * 32 + quad * 8;
          short8 bkh = ldfrag(KTh, mcol + ni * 16 + l15, c8);
          short8 bkl = ldfrag(KTl, mcol + ni * 16 + l15, c8);
          a4[ni] = __builtin_amdgcn_mfma_f32_16x16x32_bf16(avh[kst], bkh, a4[ni], 0, 0, 0);
          a4[ni] = __builtin_amdgcn_mfma_f32_16x16x32_bf16(avh[kst], bkl, a4[ni], 0, 0, 0);
          a4[ni] = __builtin_amdgcn_mfma_f32_16x16x32_bf16(avl[kst], bkh, a4[ni], 0, 0, 0);
        }
#pragma unroll
      for (int ni = 0; ni < 2; ++ni) {
        const float lce = LcEnd[mcol + ni * 16 + l15];
#pragma unroll
        for (int vv = 0; vv < 4; ++vv) {
          const int jr = mrow + quad * 4 + vv;
          const int ic = mcol + ni * 16 + l15;
          STf[jr * 64 + ic] = lce * (a4[ni][vv] + STf[jr * 64 + ic]);
        }
      }
    }
    __syncthreads();                                  // B5: tiles/STf stable for next chunk
  }
}

// ---------------- launch ----------------
extern "C" void kernel_launch(void* const* d_in, const int* in_sizes, int n_in,
                              void* d_out, int out_size, void* d_ws, size_t ws_size,
                              hipStream_t stream) {
  (void)in_sizes; (void)n_in; (void)out_size;
  const float* x   = (const float*)d_in[0];
  const float* tmx = (const float*)d_in[1];
  const float* tmw = (const float*)d_in[2];
  const float* tmk = (const float*)d_in[3];
  const float* tmv = (const float*)d_in[4];
  const float* tmr = (const float*)d_in[5];
  const float* tmg = (const float*)d_in[6];
  const float* w1  = (const float*)d_in[7];   // (C,160)
  const float* w2  = (const float*)d_in[8];   // (5,32,C)
  const float* td  = (const float*)d_in[9];   // (A)
  const float* dw1 = (const float*)d_in[10];  // (C,64)
  const float* dw2 = (const float*)d_in[11];  // (64,A)
  const float* u   = (const float*)d_in[12];  // (H,N)
  const float* Wr  = (const float*)d_in[13];
  const float* Wk  = (const float*)d_in[14];
  const float* Wv  = (const float*)d_in[15];
  const float* Wg  = (const float*)d_in[16];
  const float* Wo  = (const float*)d_in[17];
  const float* lnw = (const float*)d_in[18];
  const float* lnb = (const float*)d_in[19];

  char* ws = (char*)d_ws;
  const size_t MB = 1024 * 1024;
  // 472MB layout (proven safe footprint), lifetime-overlapped:
  // [0,64)    U0: xxx -> g (f16) -> z (f16, in place)
  // [64,80)       m5 (f32, 16MB) -> later v-f32 lower half spans [64,128)
  // [128,192) U2: bxk (w1T scratch at [128,129) pre-mix) -> v-f32 upper half
  // [192,256) U3: bxv -> dec lower half
  // [256,320) U4: bxw -> dec upper half     (dec = [192,320) f32, read-only in chunk kernel)
  // [320,384) U5: bxg -> r (bf16)
  // [384,448) U6: bxr -> k (bf16, L0)
  // [448,456)     Wf16 scratch (dw1T pre) -> Wf16 per projection
  // [464,472)     t1 (f32, 8MB)
  unsigned short* xxx  = (unsigned short*)(ws + 0 * MB);
  unsigned short* gb   = (unsigned short*)(ws + 0 * MB);     // g then z (f16)
  float*          m5   = (float*)(ws + 64 * MB);
  float*          vf   = (float*)(ws + 64 * MB);             // v f32 [64,192)
  unsigned short* w1T  = (unsigned short*)(ws + 128 * MB);
  unsigned short* bxk  = (unsigned short*)(ws + 128 * MB);
  unsigned short* bxv  = (unsigned short*)(ws + 192 * MB);
  float*          decb = (float*)(ws + 192 * MB);            // dec f32 [192,320)
  unsigned short* bxw  = (unsigned short*)(ws + 256 * MB);
  unsigned short* bxg  = (unsigned short*)(ws + 320 * MB);
  unsigned short* rb   = (unsigned short*)(ws + 320 * MB);   // r (bf16)
  unsigned short* bxr  = (unsigned short*)(ws + 384 * MB);
  unsigned short* kb   = (unsigned short*)(ws + 384 * MB);   // k bf16 (L0)
  unsigned short* dw1T = (unsigned short*)(ws + 448 * MB);
  unsigned short* Wf   = (unsigned short*)(ws + 448 * MB);   // f16 weight scratch
  float*          t1   = (float*)(ws + 464 * MB);
  // optional upgrade: k in f32 at [480,608) if workspace allows (runtime-constant branch)
  const bool kf32 = ws_size >= (size_t)616 * MB;
  float* kf = (float*)(ws + 480 * MB);

  const int nW = A_ * C_;  // 4.19M elements
  const size_t EBT = (size_t)BT_ * C_;

  // 1. token-shift mix -> xxx (f16)
  shift_mix<<<(int)(EBT / 4 / 256), 256, 0, stream>>>(x, tmx, xxx);

  // 2. m5 = tanh(xxx @ maa_w1) padded N=256
  transpose_pad<<<(256 * 2048) / 256, 256, 0, stream>>>(w1, w1T, 256, 160);
  gemm_f16<2><<<dim3(BT_ / 128, 2), 256, 0, stream>>>(xxx, w1T, m5, BT_, 256, 2048);

  // 3. five mixed inputs (f16)
  mix_lora<<<BT_ / 16, 256, 0, stream>>>(x, m5, w2, tmw, tmk, tmv, tmr, tmg,
                                         bxw, bxk, bxv, bxr, bxg);

  // 4. t1 = tanh(xw @ decay_w1) padded N=128
  transpose_pad<<<(128 * 2048) / 256, 256, 0, stream>>>(dw1, dw1T, 128, 64);
  gemm_f16<2><<<dim3(BT_ / 128, 1), 256, 0, stream>>>(bxw, dw1T, t1, BT_, 128, 2048);

  // 5-8. projections with f16 weights (order matters for slot recycling)
  conv_f16<<<nW / 256, 256, 0, stream>>>(Wg, Wf, nW);
  gemm_f16<1><<<dim3(BT_ / 128, 16), 256, 0, stream>>>(bxg, Wf, gb, BT_, 2048, 2048);
  conv_f16<<<nW / 256, 256, 0, stream>>>(Wr, Wf, nW);
  gemm_f16<0><<<dim3(BT_ / 128, 16), 256, 0, stream>>>(bxr, Wf, rb, BT_, 2048, 2048);
  conv_f16<<<nW / 256, 256, 0, stream>>>(Wk, Wf, nW);
  if (kf32) {
    gemm_f16<3><<<dim3(BT_ / 128, 16), 256, 0, stream>>>(bxk, Wf, kf, BT_, 2048, 2048);
  } else {
    gemm_f16<0><<<dim3(BT_ / 128, 16), 256, 0, stream>>>(bxk, Wf, kb, BT_, 2048, 2048);
  }
  conv_f16<<<nW / 256, 256, 0, stream>>>(Wv, Wf, nW);
  gemm_f16<3><<<dim3(BT_ / 128, 16), 256, 0, stream>>>(bxv, Wf, vf, BT_, 2048, 2048);

  // 9. dec (after bxv/bxw are dead; overlays them)
  decay_kernel<<<BT_ / 16, 256, 0, stream>>>(t1, dw2, td, decb);

  // 10. WKV6 chunk-parallel MFMA (8 waves) + fused GroupNorm*g -> z (f16, over g)
  if (kf32) {
    wkv6_chunk<1><<<256, 512, 0, stream>>>(rb, kb, kf, vf, decb, u, gb, lnw, lnb);
  } else {
    wkv6_chunk<0><<<256, 512, 0, stream>>>(rb, kb, kf, vf, decb, u, gb, lnw, lnb);
  }

  // 11. output projection: z @ Wo^T (both f16) -> d_out (f32)
  conv_f16<<<nW / 256, 256, 0, stream>>>(Wo, Wf, nW);
  gemm_f16<3><<<dim3(BT_ / 128, 16), 256, 0, stream>>>(gb, Wf, (float*)d_out, BT_, 2048, 2048);
}